// Round 1
// baseline (1896.070 us; speedup 1.0000x reference)
//
#include <hip/hip_runtime.h>

// GCN layer: conv = D^-1/2 (A+I) D^-1/2 (x W) + b ; h = x + conv ; GraphNorm ; ReLU
// Round 0: correctness-first fp32 pipeline.
//   K1 init (deg=1, zero stats) -> K2 deg atomic scatter -> K3 dis=rsqrt(deg)
//   K4 SGEMM xW = node @ W (fp32, 128x128 tile, 8x8/thread)
//   K5 h = node + b + xW*dis^2 (self-loop fused)   [into d_out]
//   K6 edge scatter: d_out[col] += xW[row]*norm    (scalar fp32 atomics)
//   K7 GraphNorm stats single pass: Sx, Sxx, count (sorted batch -> segment flush)
//   K8 finalize: meanAlpha, invstd = rsqrt(E[x^2]-2m*ma+ma^2+eps)
//   K9 normalize + ReLU in place
// Predicted: GEMM ~300us (fp32 VALU-bound), scatter ~150us (atomic-bound), total ~650us.

#define N_NODES 50000
#define N_EDGES 160000
#define DIM 512
#define N_GRAPHS 64
#define EPSV 1e-5f

__global__ __launch_bounds__(256) void k_init(float* __restrict__ deg,
                                              float* __restrict__ Sx,
                                              float* __restrict__ Sxx,
                                              float* __restrict__ cnt) {
    int i = blockIdx.x * 256 + threadIdx.x;
    if (i < N_NODES) deg[i] = 1.0f;              // self-loop weight
    if (i < N_GRAPHS * DIM) { Sx[i] = 0.f; Sxx[i] = 0.f; }
    if (i < N_GRAPHS) cnt[i] = 0.f;
}

__global__ __launch_bounds__(256) void k_deg(const int* __restrict__ ei,
                                             const float* __restrict__ ew,
                                             float* __restrict__ deg) {
    int e = blockIdx.x * 256 + threadIdx.x;
    if (e < N_EDGES) atomicAdd(&deg[ei[N_EDGES + e]], ew[e]);   // col = target
}

__global__ __launch_bounds__(256) void k_dis(float* __restrict__ deg) {
    int i = blockIdx.x * 256 + threadIdx.x;
    if (i < N_NODES) deg[i] = rsqrtf(deg[i]);    // deg >= 1 always
}

// ---- fp32 SGEMM: C[M,512] = A[M,512] * B[512,512], BM=BN=128, BK=16, 8x8/thread
__global__ __launch_bounds__(256) void k_gemm(const float* __restrict__ A,
                                              const float* __restrict__ B,
                                              float* __restrict__ C) {
    __shared__ float As[16][132];   // [k][m], pad 128->132 breaks 4-way store conflicts
    __shared__ float Bs[16][128];   // [k][n]
    const int bn = blockIdx.x;      // 0..3
    const int bm = blockIdx.y;      // 0..390
    const int tid = threadIdx.x;
    const int tx = tid & 15, ty = tid >> 4;
    const int row0 = bm * 128;
    float acc[8][8] = {};
    for (int kk = 0; kk < DIM; kk += 16) {
#pragma unroll
        for (int l = 0; l < 2; ++l) {           // A tile: 128x16 = 512 float4
            int idx = tid + l * 256;
            int m = idx >> 2;
            int k4 = (idx & 3) * 4;
            int gr = row0 + m;
            float4 a = make_float4(0.f, 0.f, 0.f, 0.f);
            if (gr < N_NODES) a = *(const float4*)&A[(size_t)gr * DIM + kk + k4];
            As[k4 + 0][m] = a.x; As[k4 + 1][m] = a.y;
            As[k4 + 2][m] = a.z; As[k4 + 3][m] = a.w;
        }
#pragma unroll
        for (int l = 0; l < 2; ++l) {           // B tile: 16x128 = 512 float4
            int idx = tid + l * 256;
            int k = idx >> 5;
            int n4 = (idx & 31) * 4;
            float4 bv = *(const float4*)&B[(size_t)(kk + k) * DIM + bn * 128 + n4];
            *(float4*)&Bs[k][n4] = bv;
        }
        __syncthreads();
#pragma unroll
        for (int k = 0; k < 16; ++k) {
            float ar[8], br[8];
            *(float4*)&ar[0] = *(const float4*)&As[k][ty * 8];
            *(float4*)&ar[4] = *(const float4*)&As[k][ty * 8 + 4];
            *(float4*)&br[0] = *(const float4*)&Bs[k][tx * 8];
            *(float4*)&br[4] = *(const float4*)&Bs[k][tx * 8 + 4];
#pragma unroll
            for (int i = 0; i < 8; ++i)
#pragma unroll
                for (int j = 0; j < 8; ++j)
                    acc[i][j] += ar[i] * br[j];
        }
        __syncthreads();
    }
#pragma unroll
    for (int i = 0; i < 8; ++i) {
        int gr = row0 + ty * 8 + i;
        if (gr < N_NODES) {
            *(float4*)&C[(size_t)gr * DIM + bn * 128 + tx * 8] =
                make_float4(acc[i][0], acc[i][1], acc[i][2], acc[i][3]);
            *(float4*)&C[(size_t)gr * DIM + bn * 128 + tx * 8 + 4] =
                make_float4(acc[i][4], acc[i][5], acc[i][6], acc[i][7]);
        }
    }
}

// h = node + b + xW * dis^2  (skip + bias + self-loop message)
__global__ __launch_bounds__(256) void k_init_h(const float* __restrict__ node,
                                                const float* __restrict__ b,
                                                const float* __restrict__ xW,
                                                const float* __restrict__ dis,
                                                float* __restrict__ out) {
    size_t idx = (size_t)blockIdx.x * 256 + threadIdx.x;   // one float4 each
    int n = (int)(idx >> 7);
    int q = ((int)idx & 127) * 4;
    if (n >= N_NODES) return;
    float s = dis[n];
    float s2 = s * s;
    float4 xv = *(const float4*)&xW[(size_t)n * DIM + q];
    float4 nd = *(const float4*)&node[(size_t)n * DIM + q];
    float4 bb = *(const float4*)&b[q];
    float4 r;
    r.x = nd.x + bb.x + xv.x * s2;
    r.y = nd.y + bb.y + xv.y * s2;
    r.z = nd.z + bb.z + xv.z * s2;
    r.w = nd.w + bb.w + xv.w * s2;
    *(float4*)&out[(size_t)n * DIM + q] = r;
}

// edge scatter: 2 edges per block, 128 threads/edge, float4 gather + 4 scalar atomics
__global__ __launch_bounds__(256) void k_edge(const int* __restrict__ ei,
                                              const float* __restrict__ ew,
                                              const float* __restrict__ dis,
                                              const float* __restrict__ xW,
                                              float* __restrict__ out) {
    int e = blockIdx.x * 2 + (threadIdx.x >> 7);
    int q = (threadIdx.x & 127) * 4;
    if (e >= N_EDGES) return;
    int r = ei[e];
    int c = ei[N_EDGES + e];
    float norm = dis[r] * ew[e] * dis[c];
    float4 x = *(const float4*)&xW[(size_t)r * DIM + q];
    float* o = &out[(size_t)c * DIM + q];
    atomicAdd(o + 0, x.x * norm);
    atomicAdd(o + 1, x.y * norm);
    atomicAdd(o + 2, x.z * norm);
    atomicAdd(o + 3, x.w * norm);
}

// single-pass per-graph stats: thread t owns dims t and t+256; sorted batch -> flush per segment
__global__ __launch_bounds__(256) void k_stats(const float* __restrict__ h,
                                               const int* __restrict__ batch,
                                               float* __restrict__ Sx,
                                               float* __restrict__ Sxx,
                                               float* __restrict__ cnt) {
    const int CH = 32;
    int n0 = blockIdx.x * CH;
    if (n0 >= N_NODES) return;
    int nEnd = n0 + CH; if (nEnd > N_NODES) nEnd = N_NODES;
    int t = threadIdx.x;
    float sx0 = 0.f, sx1 = 0.f, sxx0 = 0.f, sxx1 = 0.f;
    int cur = batch[n0];
    int seg = 0;
    for (int n = n0; n < nEnd; ++n) {
        int g = batch[n];
        if (g != cur) {                         // block-uniform branch
            atomicAdd(&Sx[cur * DIM + t], sx0);
            atomicAdd(&Sx[cur * DIM + t + 256], sx1);
            atomicAdd(&Sxx[cur * DIM + t], sxx0);
            atomicAdd(&Sxx[cur * DIM + t + 256], sxx1);
            if (t == 0) atomicAdd(&cnt[cur], (float)seg);
            sx0 = sx1 = sxx0 = sxx1 = 0.f; seg = 0; cur = g;
        }
        float a = h[(size_t)n * DIM + t];
        float c2 = h[(size_t)n * DIM + t + 256];
        sx0 += a;  sxx0 += a * a;
        sx1 += c2; sxx1 += c2 * c2;
        seg++;
    }
    atomicAdd(&Sx[cur * DIM + t], sx0);
    atomicAdd(&Sx[cur * DIM + t + 256], sx1);
    atomicAdd(&Sxx[cur * DIM + t], sxx0);
    atomicAdd(&Sxx[cur * DIM + t + 256], sxx1);
    if (t == 0) atomicAdd(&cnt[cur], (float)seg);
}

// meanAlpha = (Sx/c)*alpha ; var = Sxx/c - 2m*ma + ma^2 ; inv = rsqrt(var+eps)
__global__ __launch_bounds__(256) void k_fin(const float* __restrict__ Sx,
                                             const float* __restrict__ Sxx,
                                             const float* __restrict__ cnt,
                                             const float* __restrict__ alpha,
                                             float* __restrict__ mA,
                                             float* __restrict__ inv) {
    int i = blockIdx.x * 256 + threadIdx.x;
    if (i >= N_GRAPHS * DIM) return;
    int d = i & (DIM - 1);
    int g = i >> 9;
    float c = fmaxf(cnt[g], 1.0f);
    float m = Sx[i] / c;
    float ma = m * alpha[d];
    float var = Sxx[i] / c - 2.f * m * ma + ma * ma;
    mA[i] = ma;
    inv[i] = rsqrtf(var + EPSV);
}

__global__ __launch_bounds__(256) void k_norm(float* __restrict__ out,
                                              const int* __restrict__ batch,
                                              const float* __restrict__ mA,
                                              const float* __restrict__ inv,
                                              const float* __restrict__ gw,
                                              const float* __restrict__ gb) {
    size_t idx = (size_t)blockIdx.x * 256 + threadIdx.x;
    int n = (int)(idx >> 7);
    int q = ((int)idx & 127) * 4;
    if (n >= N_NODES) return;
    int g = batch[n];
    float4 h = *(const float4*)&out[(size_t)n * DIM + q];
    float4 ma = *(const float4*)&mA[(size_t)g * DIM + q];
    float4 iv = *(const float4*)&inv[(size_t)g * DIM + q];
    float4 w4 = *(const float4*)&gw[q];
    float4 b4 = *(const float4*)&gb[q];
    float4 r;
    r.x = fmaxf(0.f, (h.x - ma.x) * iv.x * w4.x + b4.x);
    r.y = fmaxf(0.f, (h.y - ma.y) * iv.y * w4.y + b4.y);
    r.z = fmaxf(0.f, (h.z - ma.z) * iv.z * w4.z + b4.z);
    r.w = fmaxf(0.f, (h.w - ma.w) * iv.w * w4.w + b4.w);
    *(float4*)&out[(size_t)n * DIM + q] = r;
}

extern "C" void kernel_launch(void* const* d_in, const int* in_sizes, int n_in,
                              void* d_out, int out_size, void* d_ws, size_t ws_size,
                              hipStream_t stream) {
    const float* node  = (const float*)d_in[0];
    const float* eattr = (const float*)d_in[1];
    const float* W     = (const float*)d_in[2];
    const float* b     = (const float*)d_in[3];
    const float* gw    = (const float*)d_in[4];
    const float* gb    = (const float*)d_in[5];
    const float* alpha = (const float*)d_in[6];
    const int*   ei    = (const int*)d_in[7];
    const int*   batch = (const int*)d_in[8];
    float* out = (float*)d_out;

    float* ws  = (float*)d_ws;
    float* xW  = ws;                                   // 25,600,000 f32
    float* dis = xW + (size_t)N_NODES * DIM;           // 50,000 (deg then rsqrt in place)
    float* Sx  = dis + N_NODES;                        // 32,768
    float* Sxx = Sx + N_GRAPHS * DIM;                  // 32,768
    float* cnt = Sxx + N_GRAPHS * DIM;                 // 64
    float* mA  = cnt + 64;                             // 32,768
    float* inv = mA + N_GRAPHS * DIM;                  // 32,768  (total ~98.4 MiB)

    k_init<<<196, 256, 0, stream>>>(dis, Sx, Sxx, cnt);
    k_deg<<<(N_EDGES + 255) / 256, 256, 0, stream>>>(ei, eattr, dis);
    k_dis<<<196, 256, 0, stream>>>(dis);
    dim3 ggrid(4, 391);
    k_gemm<<<ggrid, 256, 0, stream>>>(node, W, xW);
    k_init_h<<<25000, 256, 0, stream>>>(node, b, xW, dis, out);
    k_edge<<<N_EDGES / 2, 256, 0, stream>>>(ei, eattr, dis, xW, out);
    k_stats<<<(N_NODES + 31) / 32, 256, 0, stream>>>(out, batch, Sx, Sxx, cnt);
    k_fin<<<128, 256, 0, stream>>>(Sx, Sxx, cnt, alpha, mA, inv);
    k_norm<<<25000, 256, 0, stream>>>(out, batch, mA, inv, gw, gb);
}

// Round 2
// 998.170 us; speedup vs baseline: 1.8995x; 1.8995x over previous
//
#include <hip/hip_runtime.h>

// GCN layer: conv = D^-1/2 (A+I) D^-1/2 (x W) + b ; h = x + conv ; GraphNorm ; ReLU
// R1: replace 82M scalar atomics (k_edge, 1065us, 4x write-amplified) with
// device-built CSR (by target) + per-node register-accumulated gather, fused
// with skip+bias+self-loop. Atomics now: 2x160k (count + cursor) only.

#define N_NODES 50000
#define N_EDGES 160000
#define DIM 512
#define N_GRAPHS 64
#define EPSV 1e-5f

// deg=1 (self-loop), zero stats, zero per-node edge counts
__global__ __launch_bounds__(256) void k_init(float* __restrict__ deg,
                                              float* __restrict__ Sx,
                                              float* __restrict__ Sxx,
                                              float* __restrict__ cntg,
                                              int* __restrict__ ecnt) {
    int i = blockIdx.x * 256 + threadIdx.x;
    if (i < N_NODES) { deg[i] = 1.0f; ecnt[i] = 0; }
    if (i < N_GRAPHS * DIM) { Sx[i] = 0.f; Sxx[i] = 0.f; }
    if (i < N_GRAPHS) cntg[i] = 0.f;
}

__global__ __launch_bounds__(256) void k_deg(const int* __restrict__ ei,
                                             const float* __restrict__ ew,
                                             float* __restrict__ deg,
                                             int* __restrict__ ecnt) {
    int e = blockIdx.x * 256 + threadIdx.x;
    if (e < N_EDGES) {
        int c = ei[N_EDGES + e];
        atomicAdd(&deg[c], ew[e]);
        atomicAdd(&ecnt[c], 1);
    }
}

__global__ __launch_bounds__(256) void k_dis(float* __restrict__ deg) {
    int i = blockIdx.x * 256 + threadIdx.x;
    if (i < N_NODES) deg[i] = rsqrtf(deg[i]);
}

// single-block exclusive scan of ecnt[50000] -> rowptr[50001], cursor copy
__global__ __launch_bounds__(1024) void k_scan(const int* __restrict__ ecnt,
                                               int* __restrict__ rowptr,
                                               int* __restrict__ cursor) {
    const int CH = (N_NODES + 1023) / 1024;   // 49
    __shared__ int ssum[1024];
    int t = threadIdx.x;
    int lo = t * CH, hi = min(lo + CH, N_NODES);
    int s = 0;
    for (int i = lo; i < hi; ++i) s += ecnt[i];
    ssum[t] = s;
    __syncthreads();
    // Hillis-Steele inclusive scan on 1024 partials
    for (int off = 1; off < 1024; off <<= 1) {
        int v = (t >= off) ? ssum[t - off] : 0;
        __syncthreads();
        ssum[t] += v;
        __syncthreads();
    }
    int base = (t == 0) ? 0 : ssum[t - 1];    // exclusive prefix of this chunk
    for (int i = lo; i < hi; ++i) {
        rowptr[i] = base;
        cursor[i] = base;
        base += ecnt[i];
    }
    if (t == 1023) rowptr[N_NODES] = ssum[1023];
}

// fill CSR: srcs[pos]=row, wts[pos]=ew*dis[row]
__global__ __launch_bounds__(256) void k_fill(const int* __restrict__ ei,
                                              const float* __restrict__ ew,
                                              const float* __restrict__ dis,
                                              int* __restrict__ cursor,
                                              int* __restrict__ srcs,
                                              float* __restrict__ wts) {
    int e = blockIdx.x * 256 + threadIdx.x;
    if (e >= N_EDGES) return;
    int r = ei[e];
    int c = ei[N_EDGES + e];
    int pos = atomicAdd(&cursor[c], 1);
    srcs[pos] = r;
    wts[pos] = ew[e] * dis[r];
}

// ---- fp32 SGEMM: C[M,512] = A[M,512] * B[512,512], BM=BN=128, BK=16, 8x8/thread
__global__ __launch_bounds__(256) void k_gemm(const float* __restrict__ A,
                                              const float* __restrict__ B,
                                              float* __restrict__ C) {
    __shared__ float As[16][132];
    __shared__ float Bs[16][128];
    const int bn = blockIdx.x;
    const int bm = blockIdx.y;
    const int tid = threadIdx.x;
    const int tx = tid & 15, ty = tid >> 4;
    const int row0 = bm * 128;
    float acc[8][8] = {};
    for (int kk = 0; kk < DIM; kk += 16) {
#pragma unroll
        for (int l = 0; l < 2; ++l) {
            int idx = tid + l * 256;
            int m = idx >> 2;
            int k4 = (idx & 3) * 4;
            int gr = row0 + m;
            float4 a = make_float4(0.f, 0.f, 0.f, 0.f);
            if (gr < N_NODES) a = *(const float4*)&A[(size_t)gr * DIM + kk + k4];
            As[k4 + 0][m] = a.x; As[k4 + 1][m] = a.y;
            As[k4 + 2][m] = a.z; As[k4 + 3][m] = a.w;
        }
#pragma unroll
        for (int l = 0; l < 2; ++l) {
            int idx = tid + l * 256;
            int k = idx >> 5;
            int n4 = (idx & 31) * 4;
            float4 bv = *(const float4*)&B[(size_t)(kk + k) * DIM + bn * 128 + n4];
            *(float4*)&Bs[k][n4] = bv;
        }
        __syncthreads();
#pragma unroll
        for (int k = 0; k < 16; ++k) {
            float ar[8], br[8];
            *(float4*)&ar[0] = *(const float4*)&As[k][ty * 8];
            *(float4*)&ar[4] = *(const float4*)&As[k][ty * 8 + 4];
            *(float4*)&br[0] = *(const float4*)&Bs[k][tx * 8];
            *(float4*)&br[4] = *(const float4*)&Bs[k][tx * 8 + 4];
#pragma unroll
            for (int i = 0; i < 8; ++i)
#pragma unroll
                for (int j = 0; j < 8; ++j)
                    acc[i][j] += ar[i] * br[j];
        }
        __syncthreads();
    }
#pragma unroll
    for (int i = 0; i < 8; ++i) {
        int gr = row0 + ty * 8 + i;
        if (gr < N_NODES) {
            *(float4*)&C[(size_t)gr * DIM + bn * 128 + tx * 8] =
                make_float4(acc[i][0], acc[i][1], acc[i][2], acc[i][3]);
            *(float4*)&C[(size_t)gr * DIM + bn * 128 + tx * 8 + 4] =
                make_float4(acc[i][4], acc[i][5], acc[i][6], acc[i][7]);
        }
    }
}

// fused gather: out[n] = node[n] + b + dis[n]*( dis[n]*xW[n] + sum_i wts[i]*xW[srcs[i]] )
// 2 nodes/block, 128 lanes per node, float4 per lane
__global__ __launch_bounds__(256) void k_gather(const int* __restrict__ rowptr,
                                                const int* __restrict__ srcs,
                                                const float* __restrict__ wts,
                                                const float* __restrict__ xW,
                                                const float* __restrict__ node,
                                                const float* __restrict__ b,
                                                const float* __restrict__ dis,
                                                float* __restrict__ out) {
    int n = blockIdx.x * 2 + (threadIdx.x >> 7);
    int q = (threadIdx.x & 127) * 4;
    if (n >= N_NODES) return;
    float dn = dis[n];
    int lo = rowptr[n], hi = rowptr[n + 1];
    float4 x = *(const float4*)&xW[(size_t)n * DIM + q];
    float4 acc;                       // dis[n]*xW[n] (self-loop term, pre-outer-scale)
    acc.x = dn * x.x; acc.y = dn * x.y; acc.z = dn * x.z; acc.w = dn * x.w;
    for (int i = lo; i < hi; ++i) {
        int s = srcs[i];              // broadcast across lanes
        float w = wts[i];             // = ew * dis[src]
        float4 xv = *(const float4*)&xW[(size_t)s * DIM + q];
        acc.x += w * xv.x; acc.y += w * xv.y;
        acc.z += w * xv.z; acc.w += w * xv.w;
    }
    float4 nd = *(const float4*)&node[(size_t)n * DIM + q];
    float4 bb = *(const float4*)&b[q];
    float4 r;
    r.x = nd.x + bb.x + dn * acc.x;
    r.y = nd.y + bb.y + dn * acc.y;
    r.z = nd.z + bb.z + dn * acc.z;
    r.w = nd.w + bb.w + dn * acc.w;
    *(float4*)&out[(size_t)n * DIM + q] = r;
}

// per-graph stats: thread t owns dims t, t+256; sorted batch -> segment flush
__global__ __launch_bounds__(256) void k_stats(const float* __restrict__ h,
                                               const int* __restrict__ batch,
                                               float* __restrict__ Sx,
                                               float* __restrict__ Sxx,
                                               float* __restrict__ cntg) {
    const int CH = 32;
    int n0 = blockIdx.x * CH;
    if (n0 >= N_NODES) return;
    int nEnd = n0 + CH; if (nEnd > N_NODES) nEnd = N_NODES;
    int t = threadIdx.x;
    float sx0 = 0.f, sx1 = 0.f, sxx0 = 0.f, sxx1 = 0.f;
    int cur = batch[n0];
    int seg = 0;
    for (int n = n0; n < nEnd; ++n) {
        int g = batch[n];
        if (g != cur) {
            atomicAdd(&Sx[cur * DIM + t], sx0);
            atomicAdd(&Sx[cur * DIM + t + 256], sx1);
            atomicAdd(&Sxx[cur * DIM + t], sxx0);
            atomicAdd(&Sxx[cur * DIM + t + 256], sxx1);
            if (t == 0) atomicAdd(&cntg[cur], (float)seg);
            sx0 = sx1 = sxx0 = sxx1 = 0.f; seg = 0; cur = g;
        }
        float a = h[(size_t)n * DIM + t];
        float c2 = h[(size_t)n * DIM + t + 256];
        sx0 += a;  sxx0 += a * a;
        sx1 += c2; sxx1 += c2 * c2;
        seg++;
    }
    atomicAdd(&Sx[cur * DIM + t], sx0);
    atomicAdd(&Sx[cur * DIM + t + 256], sx1);
    atomicAdd(&Sxx[cur * DIM + t], sxx0);
    atomicAdd(&Sxx[cur * DIM + t + 256], sxx1);
    if (t == 0) atomicAdd(&cntg[cur], (float)seg);
}

__global__ __launch_bounds__(256) void k_fin(const float* __restrict__ Sx,
                                             const float* __restrict__ Sxx,
                                             const float* __restrict__ cntg,
                                             const float* __restrict__ alpha,
                                             float* __restrict__ mA,
                                             float* __restrict__ inv) {
    int i = blockIdx.x * 256 + threadIdx.x;
    if (i >= N_GRAPHS * DIM) return;
    int d = i & (DIM - 1);
    int g = i >> 9;
    float c = fmaxf(cntg[g], 1.0f);
    float m = Sx[i] / c;
    float ma = m * alpha[d];
    float var = Sxx[i] / c - 2.f * m * ma + ma * ma;
    mA[i] = ma;
    inv[i] = rsqrtf(var + EPSV);
}

__global__ __launch_bounds__(256) void k_norm(float* __restrict__ out,
                                              const int* __restrict__ batch,
                                              const float* __restrict__ mA,
                                              const float* __restrict__ inv,
                                              const float* __restrict__ gw,
                                              const float* __restrict__ gb) {
    size_t idx = (size_t)blockIdx.x * 256 + threadIdx.x;
    int n = (int)(idx >> 7);
    int q = ((int)idx & 127) * 4;
    if (n >= N_NODES) return;
    int g = batch[n];
    float4 h = *(const float4*)&out[(size_t)n * DIM + q];
    float4 ma = *(const float4*)&mA[(size_t)g * DIM + q];
    float4 iv = *(const float4*)&inv[(size_t)g * DIM + q];
    float4 w4 = *(const float4*)&gw[q];
    float4 b4 = *(const float4*)&gb[q];
    float4 r;
    r.x = fmaxf(0.f, (h.x - ma.x) * iv.x * w4.x + b4.x);
    r.y = fmaxf(0.f, (h.y - ma.y) * iv.y * w4.y + b4.y);
    r.z = fmaxf(0.f, (h.z - ma.z) * iv.z * w4.z + b4.z);
    r.w = fmaxf(0.f, (h.w - ma.w) * iv.w * w4.w + b4.w);
    *(float4*)&out[(size_t)n * DIM + q] = r;
}

extern "C" void kernel_launch(void* const* d_in, const int* in_sizes, int n_in,
                              void* d_out, int out_size, void* d_ws, size_t ws_size,
                              hipStream_t stream) {
    const float* node  = (const float*)d_in[0];
    const float* eattr = (const float*)d_in[1];
    const float* W     = (const float*)d_in[2];
    const float* b     = (const float*)d_in[3];
    const float* gw    = (const float*)d_in[4];
    const float* gb    = (const float*)d_in[5];
    const float* alpha = (const float*)d_in[6];
    const int*   ei    = (const int*)d_in[7];
    const int*   batch = (const int*)d_in[8];
    float* out = (float*)d_out;

    float* ws  = (float*)d_ws;
    float* xW   = ws;                                  // 25,600,000 f32
    float* dis  = xW + (size_t)N_NODES * DIM;          // 50,000
    float* Sx   = dis + N_NODES;                       // 32,768
    float* Sxx  = Sx + N_GRAPHS * DIM;                 // 32,768
    float* cntg = Sxx + N_GRAPHS * DIM;                // 64
    float* mA   = cntg + 64;                           // 32,768
    float* inv  = mA + N_GRAPHS * DIM;                 // 32,768
    float* wts  = inv + N_GRAPHS * DIM;                // 160,000
    int* ecnt   = (int*)(wts + N_EDGES);               // 50,000
    int* rowptr = ecnt + N_NODES;                      // 50,001
    int* cursor = rowptr + N_NODES + 1;                // 50,000
    int* srcs   = cursor + N_NODES;                    // 160,000   (total ~104 MiB)

    k_init<<<196, 256, 0, stream>>>(dis, Sx, Sxx, cntg, ecnt);
    k_deg<<<(N_EDGES + 255) / 256, 256, 0, stream>>>(ei, eattr, dis, ecnt);
    k_dis<<<196, 256, 0, stream>>>(dis);
    k_scan<<<1, 1024, 0, stream>>>(ecnt, rowptr, cursor);
    k_fill<<<(N_EDGES + 255) / 256, 256, 0, stream>>>(ei, eattr, dis, cursor, srcs, wts);
    dim3 ggrid(4, 391);
    k_gemm<<<ggrid, 256, 0, stream>>>(node, W, xW);
    k_gather<<<N_NODES / 2, 256, 0, stream>>>(rowptr, srcs, wts, xW, node, b, dis, out);
    k_stats<<<(N_NODES + 31) / 32, 256, 0, stream>>>(out, batch, Sx, Sxx, cntg);
    k_fin<<<128, 256, 0, stream>>>(Sx, Sxx, cntg, alpha, mA, inv);
    k_norm<<<25000, 256, 0, stream>>>(out, batch, mA, inv, gw, gb);
}

// Round 3
// 520.341 us; speedup vs baseline: 3.6439x; 1.9183x over previous
//
#include <hip/hip_runtime.h>

// GCN layer: conv = D^-1/2 (A+I) D^-1/2 (x W) + b ; h = x + conv ; GraphNorm ; ReLU
// R2: bf16 MFMA GEMM (m97 structure: 128x128 tile, BK=64, global_load_lds w=16,
// 16x16x32 bf16 MFMA, fp32 acc). node cast to bf16 (padded 50048 rows), W cast+
// transposed to Wt[n][k]. xW stored bf16 -> gather traffic halved, L3-resident.

#define N_NODES 50000
#define PADN    50048
#define N_EDGES 160000
#define DIM 512
#define N_GRAPHS 64
#define EPSV 1e-5f

typedef short short8 __attribute__((ext_vector_type(8)));
typedef float floatx4 __attribute__((ext_vector_type(4)));

__device__ __forceinline__ unsigned short f2bf(float x) {
    unsigned int u = __float_as_uint(x);
    u += 0x7FFFu + ((u >> 16) & 1u);          // round-to-nearest-even
    return (unsigned short)(u >> 16);
}
__device__ __forceinline__ float bf2f(unsigned short s) {
    return __uint_as_float(((unsigned int)s) << 16);
}

// ---------- setup kernels ----------
__global__ __launch_bounds__(256) void k_init(float* __restrict__ deg,
                                              float* __restrict__ Sx,
                                              float* __restrict__ Sxx,
                                              float* __restrict__ cntg,
                                              int* __restrict__ ecnt) {
    int i = blockIdx.x * 256 + threadIdx.x;
    if (i < N_NODES) { deg[i] = 1.0f; ecnt[i] = 0; }
    if (i < N_GRAPHS * DIM) { Sx[i] = 0.f; Sxx[i] = 0.f; }
    if (i < N_GRAPHS) cntg[i] = 0.f;
}

__global__ __launch_bounds__(256) void k_deg(const int* __restrict__ ei,
                                             const float* __restrict__ ew,
                                             float* __restrict__ deg,
                                             int* __restrict__ ecnt) {
    int e = blockIdx.x * 256 + threadIdx.x;
    if (e < N_EDGES) {
        int c = ei[N_EDGES + e];
        atomicAdd(&deg[c], ew[e]);
        atomicAdd(&ecnt[c], 1);
    }
}

__global__ __launch_bounds__(256) void k_dis(float* __restrict__ deg) {
    int i = blockIdx.x * 256 + threadIdx.x;
    if (i < N_NODES) deg[i] = rsqrtf(deg[i]);
}

__global__ __launch_bounds__(1024) void k_scan(const int* __restrict__ ecnt,
                                               int* __restrict__ rowptr,
                                               int* __restrict__ cursor) {
    const int CH = (N_NODES + 1023) / 1024;
    __shared__ int ssum[1024];
    int t = threadIdx.x;
    int lo = t * CH, hi = min(lo + CH, N_NODES);
    int s = 0;
    for (int i = lo; i < hi; ++i) s += ecnt[i];
    ssum[t] = s;
    __syncthreads();
    for (int off = 1; off < 1024; off <<= 1) {
        int v = (t >= off) ? ssum[t - off] : 0;
        __syncthreads();
        ssum[t] += v;
        __syncthreads();
    }
    int base = (t == 0) ? 0 : ssum[t - 1];
    for (int i = lo; i < hi; ++i) {
        rowptr[i] = base;
        cursor[i] = base;
        base += ecnt[i];
    }
    if (t == 1023) rowptr[N_NODES] = ssum[1023];
}

__global__ __launch_bounds__(256) void k_fill(const int* __restrict__ ei,
                                              const float* __restrict__ ew,
                                              const float* __restrict__ dis,
                                              int* __restrict__ cursor,
                                              int* __restrict__ srcs,
                                              float* __restrict__ wts) {
    int e = blockIdx.x * 256 + threadIdx.x;
    if (e >= N_EDGES) return;
    int r = ei[e];
    int c = ei[N_EDGES + e];
    int pos = atomicAdd(&cursor[c], 1);
    srcs[pos] = r;
    wts[pos] = ew[e] * dis[r];
}

// node fp32 -> bf16, rows >= N_NODES zero-padded. 8 elems/thread.
__global__ __launch_bounds__(256) void k_cast(const float* __restrict__ node,
                                              short* __restrict__ nodeB) {
    size_t idx = (size_t)blockIdx.x * 256 + threadIdx.x;
    size_t base = idx * 8;
    int row = (int)(base >> 9);
    int4 o;
    if (row >= N_NODES) {
        o = make_int4(0, 0, 0, 0);
    } else {
        float4 a = *(const float4*)&node[base];
        float4 c = *(const float4*)&node[base + 4];
        o.x = ((unsigned)f2bf(a.y) << 16) | f2bf(a.x);
        o.y = ((unsigned)f2bf(a.w) << 16) | f2bf(a.z);
        o.z = ((unsigned)f2bf(c.y) << 16) | f2bf(c.x);
        o.w = ((unsigned)f2bf(c.w) << 16) | f2bf(c.z);
    }
    *(int4*)&nodeB[base] = o;
}

// W[k][n] fp32 -> Wt[n][k] bf16 (512x512, tiny)
__global__ __launch_bounds__(256) void k_prep_w(const float* __restrict__ W,
                                                short* __restrict__ Wt) {
    int i = blockIdx.x * 256 + threadIdx.x;   // 262144 total
    int k = i >> 9, n = i & 511;
    Wt[n * 512 + k] = (short)f2bf(W[i]);
}

// ---------- bf16 MFMA GEMM: C[PADN,512] = nodeB @ Wt^T ----------
// 128x128 tile, BK=64, 4 waves (each 64x64 = 4x4 of 16x16x32 MFMA)
__global__ __launch_bounds__(256) void k_gemm_mfma(const short* __restrict__ Abf,
                                                   const short* __restrict__ Bt,
                                                   short* __restrict__ Cbf) {
    __shared__ short As[128 * 64];   // [m][k] row-major, 16 KB
    __shared__ short Bs[128 * 64];   // [n][k] row-major, 16 KB
    const int tid  = threadIdx.x;
    const int wave = tid >> 6;
    const int lane = tid & 63;
    const int l16  = lane & 15;
    const int quad = lane >> 4;
    const int row0 = blockIdx.y * 128;
    const int col0 = blockIdx.x * 128;
    const int mb = (wave >> 1) * 64;
    const int nb = (wave & 1) * 64;

    floatx4 acc[4][4];
    const floatx4 z = {0.f, 0.f, 0.f, 0.f};
#pragma unroll
    for (int i = 0; i < 4; ++i)
#pragma unroll
        for (int j = 0; j < 4; ++j) acc[i][j] = z;

    const int srow = lane >> 3;          // 0..7 row within 8-row segment
    const int scol = (lane & 7) * 8;     // 0..56 k-offset

    for (int kk = 0; kk < DIM; kk += 64) {
#pragma unroll
        for (int j = 0; j < 4; ++j) {
            int seg = wave * 4 + j;       // 16 segments of 8 rows
            int r = seg * 8 + srow;
            __builtin_amdgcn_global_load_lds(
                (const __attribute__((address_space(1))) void*)(Abf + (size_t)(row0 + r) * DIM + kk + scol),
                (__attribute__((address_space(3))) void*)(As + seg * 512 + lane * 8),
                16, 0, 0);
            __builtin_amdgcn_global_load_lds(
                (const __attribute__((address_space(1))) void*)(Bt + (size_t)(col0 + r) * DIM + kk + scol),
                (__attribute__((address_space(3))) void*)(Bs + seg * 512 + lane * 8),
                16, 0, 0);
        }
        __syncthreads();
#pragma unroll
        for (int kh = 0; kh < 2; ++kh) {
            short8 af[4], bfr[4];
#pragma unroll
            for (int i = 0; i < 4; ++i)
                af[i] = *(const short8*)&As[(mb + i * 16 + l16) * 64 + kh * 32 + quad * 8];
#pragma unroll
            for (int j = 0; j < 4; ++j)
                bfr[j] = *(const short8*)&Bs[(nb + j * 16 + l16) * 64 + kh * 32 + quad * 8];
#pragma unroll
            for (int i = 0; i < 4; ++i)
#pragma unroll
                for (int j = 0; j < 4; ++j)
                    acc[i][j] = __builtin_amdgcn_mfma_f32_16x16x32_bf16(af[i], bfr[j], acc[i][j], 0, 0, 0);
        }
        __syncthreads();
    }
    // epilogue: C/D layout col=lane&15, row=quad*4+r ; store bf16 (PADN-padded, no guard)
#pragma unroll
    for (int i = 0; i < 4; ++i)
#pragma unroll
        for (int j = 0; j < 4; ++j) {
            int col = col0 + nb + j * 16 + l16;
#pragma unroll
            for (int r = 0; r < 4; ++r) {
                int row = row0 + mb + i * 16 + quad * 4 + r;
                Cbf[(size_t)row * DIM + col] = (short)f2bf(acc[i][j][r]);
            }
        }
}

// fused gather: out[n] = node[n] + b + dis[n]*( dis[n]*xW[n] + sum wts[i]*xW[srcs[i]] )
// 2 nodes/block, 128 lanes/node, 4 bf16 dims/lane
__global__ __launch_bounds__(256) void k_gather(const int* __restrict__ rowptr,
                                                const int* __restrict__ srcs,
                                                const float* __restrict__ wts,
                                                const short* __restrict__ xWb,
                                                const float* __restrict__ node,
                                                const float* __restrict__ b,
                                                const float* __restrict__ dis,
                                                float* __restrict__ out) {
    int n = blockIdx.x * 2 + (threadIdx.x >> 7);
    int q = (threadIdx.x & 127) * 4;
    if (n >= N_NODES) return;
    float dn = dis[n];
    int lo = rowptr[n], hi = rowptr[n + 1];
    ushort4 xs = *(const ushort4*)&xWb[(size_t)n * DIM + q];
    float4 acc;
    acc.x = dn * bf2f(xs.x); acc.y = dn * bf2f(xs.y);
    acc.z = dn * bf2f(xs.z); acc.w = dn * bf2f(xs.w);
    for (int i = lo; i < hi; ++i) {
        int s = srcs[i];
        float w = wts[i];
        ushort4 v = *(const ushort4*)&xWb[(size_t)s * DIM + q];
        acc.x += w * bf2f(v.x); acc.y += w * bf2f(v.y);
        acc.z += w * bf2f(v.z); acc.w += w * bf2f(v.w);
    }
    float4 nd = *(const float4*)&node[(size_t)n * DIM + q];
    float4 bb = *(const float4*)&b[q];
    float4 r;
    r.x = nd.x + bb.x + dn * acc.x;
    r.y = nd.y + bb.y + dn * acc.y;
    r.z = nd.z + bb.z + dn * acc.z;
    r.w = nd.w + bb.w + dn * acc.w;
    *(float4*)&out[(size_t)n * DIM + q] = r;
}

// per-graph stats: thread t owns dims t, t+256; sorted batch -> segment flush
__global__ __launch_bounds__(256) void k_stats(const float* __restrict__ h,
                                               const int* __restrict__ batch,
                                               float* __restrict__ Sx,
                                               float* __restrict__ Sxx,
                                               float* __restrict__ cntg) {
    const int CH = 32;
    int n0 = blockIdx.x * CH;
    if (n0 >= N_NODES) return;
    int nEnd = n0 + CH; if (nEnd > N_NODES) nEnd = N_NODES;
    int t = threadIdx.x;
    float sx0 = 0.f, sx1 = 0.f, sxx0 = 0.f, sxx1 = 0.f;
    int cur = batch[n0];
    int seg = 0;
    for (int n = n0; n < nEnd; ++n) {
        int g = batch[n];
        if (g != cur) {
            atomicAdd(&Sx[cur * DIM + t], sx0);
            atomicAdd(&Sx[cur * DIM + t + 256], sx1);
            atomicAdd(&Sxx[cur * DIM + t], sxx0);
            atomicAdd(&Sxx[cur * DIM + t + 256], sxx1);
            if (t == 0) atomicAdd(&cntg[cur], (float)seg);
            sx0 = sx1 = sxx0 = sxx1 = 0.f; seg = 0; cur = g;
        }
        float a = h[(size_t)n * DIM + t];
        float c2 = h[(size_t)n * DIM + t + 256];
        sx0 += a;  sxx0 += a * a;
        sx1 += c2; sxx1 += c2 * c2;
        seg++;
    }
    atomicAdd(&Sx[cur * DIM + t], sx0);
    atomicAdd(&Sx[cur * DIM + t + 256], sx1);
    atomicAdd(&Sxx[cur * DIM + t], sxx0);
    atomicAdd(&Sxx[cur * DIM + t + 256], sxx1);
    if (t == 0) atomicAdd(&cntg[cur], (float)seg);
}

__global__ __launch_bounds__(256) void k_fin(const float* __restrict__ Sx,
                                             const float* __restrict__ Sxx,
                                             const float* __restrict__ cntg,
                                             const float* __restrict__ alpha,
                                             float* __restrict__ mA,
                                             float* __restrict__ inv) {
    int i = blockIdx.x * 256 + threadIdx.x;
    if (i >= N_GRAPHS * DIM) return;
    int d = i & (DIM - 1);
    int g = i >> 9;
    float c = fmaxf(cntg[g], 1.0f);
    float m = Sx[i] / c;
    float ma = m * alpha[d];
    float var = Sxx[i] / c - 2.f * m * ma + ma * ma;
    mA[i] = ma;
    inv[i] = rsqrtf(var + EPSV);
}

__global__ __launch_bounds__(256) void k_norm(float* __restrict__ out,
                                              const int* __restrict__ batch,
                                              const float* __restrict__ mA,
                                              const float* __restrict__ inv,
                                              const float* __restrict__ gw,
                                              const float* __restrict__ gb) {
    size_t idx = (size_t)blockIdx.x * 256 + threadIdx.x;
    int n = (int)(idx >> 7);
    int q = ((int)idx & 127) * 4;
    if (n >= N_NODES) return;
    int g = batch[n];
    float4 h = *(const float4*)&out[(size_t)n * DIM + q];
    float4 ma = *(const float4*)&mA[(size_t)g * DIM + q];
    float4 iv = *(const float4*)&inv[(size_t)g * DIM + q];
    float4 w4 = *(const float4*)&gw[q];
    float4 b4 = *(const float4*)&gb[q];
    float4 r;
    r.x = fmaxf(0.f, (h.x - ma.x) * iv.x * w4.x + b4.x);
    r.y = fmaxf(0.f, (h.y - ma.y) * iv.y * w4.y + b4.y);
    r.z = fmaxf(0.f, (h.z - ma.z) * iv.z * w4.z + b4.z);
    r.w = fmaxf(0.f, (h.w - ma.w) * iv.w * w4.w + b4.w);
    *(float4*)&out[(size_t)n * DIM + q] = r;
}

extern "C" void kernel_launch(void* const* d_in, const int* in_sizes, int n_in,
                              void* d_out, int out_size, void* d_ws, size_t ws_size,
                              hipStream_t stream) {
    const float* node  = (const float*)d_in[0];
    const float* eattr = (const float*)d_in[1];
    const float* W     = (const float*)d_in[2];
    const float* b     = (const float*)d_in[3];
    const float* gw    = (const float*)d_in[4];
    const float* gb    = (const float*)d_in[5];
    const float* alpha = (const float*)d_in[6];
    const int*   ei    = (const int*)d_in[7];
    const int*   batch = (const int*)d_in[8];
    float* out = (float*)d_out;

    short* nodeB = (short*)d_ws;                       // PADN*512 bf16
    short* xWb   = nodeB + (size_t)PADN * DIM;         // PADN*512 bf16
    short* Wt    = xWb + (size_t)PADN * DIM;           // 512*512 bf16
    float* dis   = (float*)(Wt + DIM * DIM);           // 50,000
    float* Sx    = dis + N_NODES;                      // 32,768
    float* Sxx   = Sx + N_GRAPHS * DIM;                // 32,768
    float* cntg  = Sxx + N_GRAPHS * DIM;               // 64
    float* mA    = cntg + 64;                          // 32,768
    float* inv   = mA + N_GRAPHS * DIM;                // 32,768
    float* wts   = inv + N_GRAPHS * DIM;               // 160,000
    int* ecnt    = (int*)(wts + N_EDGES);              // 50,000
    int* rowptr  = ecnt + N_NODES;                     // 50,001
    int* cursor  = rowptr + N_NODES + 1;               // 50,000
    int* srcs    = cursor + N_NODES;                   // 160,000  (~106 MiB total)

    k_init<<<196, 256, 0, stream>>>(dis, Sx, Sxx, cntg, ecnt);
    k_deg<<<(N_EDGES + 255) / 256, 256, 0, stream>>>(ei, eattr, dis, ecnt);
    k_dis<<<196, 256, 0, stream>>>(dis);
    k_scan<<<1, 1024, 0, stream>>>(ecnt, rowptr, cursor);
    k_fill<<<(N_EDGES + 255) / 256, 256, 0, stream>>>(ei, eattr, dis, cursor, srcs, wts);
    k_cast<<<(PADN * DIM / 8 + 255) / 256, 256, 0, stream>>>(node, nodeB);
    k_prep_w<<<(DIM * DIM + 255) / 256, 256, 0, stream>>>(W, Wt);
    dim3 ggrid(4, PADN / 128);   // 4 x 391
    k_gemm_mfma<<<ggrid, 256, 0, stream>>>(nodeB, Wt, xWb);
    k_gather<<<N_NODES / 2, 256, 0, stream>>>(rowptr, srcs, wts, xWb, node, b, dis, out);
    k_stats<<<(N_NODES + 31) / 32, 256, 0, stream>>>(out, batch, Sx, Sxx, cntg);
    k_fin<<<128, 256, 0, stream>>>(Sx, Sxx, cntg, alpha, mA, inv);
    k_norm<<<25000, 256, 0, stream>>>(out, batch, mA, inv, gw, gb);
}

// Round 4
// 418.777 us; speedup vs baseline: 4.5276x; 1.2425x over previous
//
#include <hip/hip_runtime.h>

// GCN layer: conv = D^-1/2 (A+I) D^-1/2 (x W) + b ; h = x + conv ; GraphNorm ; ReLU
// R3: the single-block CSR scan was the #1 dispatch (111us, 0.14% occupancy,
// latency-bound on 1 CU). Replaced with 3-kernel hierarchical scan:
//   scanA: 196 blocks reduce 256 counts -> bsum ; scanB: 1 block scans bsum ;
//   scanC: intra-block exclusive scan + base -> rowptr/cursor (+ dis=rsqrt fused).

#define N_NODES 50000
#define PADN    50048
#define N_EDGES 160000
#define DIM 512
#define N_GRAPHS 64
#define EPSV 1e-5f
#define NBLK 196            // ceil(50000/256)

typedef short short8 __attribute__((ext_vector_type(8)));
typedef float floatx4 __attribute__((ext_vector_type(4)));

__device__ __forceinline__ unsigned short f2bf(float x) {
    unsigned int u = __float_as_uint(x);
    u += 0x7FFFu + ((u >> 16) & 1u);
    return (unsigned short)(u >> 16);
}
__device__ __forceinline__ float bf2f(unsigned short s) {
    return __uint_as_float(((unsigned int)s) << 16);
}

// ---------- setup ----------
__global__ __launch_bounds__(256) void k_init(float* __restrict__ deg,
                                              float* __restrict__ Sx,
                                              float* __restrict__ Sxx,
                                              float* __restrict__ cntg,
                                              int* __restrict__ ecnt) {
    int i = blockIdx.x * 256 + threadIdx.x;
    if (i < N_NODES) { deg[i] = 1.0f; ecnt[i] = 0; }
    if (i < N_GRAPHS * DIM) { Sx[i] = 0.f; Sxx[i] = 0.f; }
    if (i < N_GRAPHS) cntg[i] = 0.f;
}

__global__ __launch_bounds__(256) void k_deg(const int* __restrict__ ei,
                                             const float* __restrict__ ew,
                                             float* __restrict__ deg,
                                             int* __restrict__ ecnt) {
    int e = blockIdx.x * 256 + threadIdx.x;
    if (e < N_EDGES) {
        int c = ei[N_EDGES + e];
        atomicAdd(&deg[c], ew[e]);
        atomicAdd(&ecnt[c], 1);
    }
}

// scanA: per-block sum of 256 counts
__global__ __launch_bounds__(256) void k_scanA(const int* __restrict__ ecnt,
                                               int* __restrict__ bsum) {
    int i = blockIdx.x * 256 + threadIdx.x;
    int v = (i < N_NODES) ? ecnt[i] : 0;
#pragma unroll
    for (int off = 32; off; off >>= 1) v += __shfl_down(v, off, 64);
    __shared__ int ws[4];
    if ((threadIdx.x & 63) == 0) ws[threadIdx.x >> 6] = v;
    __syncthreads();
    if (threadIdx.x == 0) bsum[blockIdx.x] = ws[0] + ws[1] + ws[2] + ws[3];
}

// scanB: exclusive scan of bsum[NBLK] (one block)
__global__ __launch_bounds__(256) void k_scanB(const int* __restrict__ bsum,
                                               int* __restrict__ bbase) {
    __shared__ int s[256];
    int t = threadIdx.x;
    int v = (t < NBLK) ? bsum[t] : 0;
    s[t] = v;
    __syncthreads();
#pragma unroll
    for (int off = 1; off < 256; off <<= 1) {
        int u = (t >= off) ? s[t - off] : 0;
        __syncthreads();
        s[t] += u;
        __syncthreads();
    }
    if (t <= NBLK) bbase[t] = (t == 0) ? 0 : s[t - 1];
}

// scanC: intra-block exclusive scan + block base -> rowptr/cursor ; dis=rsqrt(deg)
__global__ __launch_bounds__(256) void k_scanC(const int* __restrict__ ecnt,
                                               const int* __restrict__ bbase,
                                               int* __restrict__ rowptr,
                                               int* __restrict__ cursor,
                                               float* __restrict__ deg) {
    __shared__ int s[256];
    int t = threadIdx.x;
    int i = blockIdx.x * 256 + t;
    int v = (i < N_NODES) ? ecnt[i] : 0;
    s[t] = v;
    __syncthreads();
#pragma unroll
    for (int off = 1; off < 256; off <<= 1) {
        int u = (t >= off) ? s[t - off] : 0;
        __syncthreads();
        s[t] += u;
        __syncthreads();
    }
    int excl = s[t] - v + bbase[blockIdx.x];
    if (i <= N_NODES) rowptr[i] = excl;      // i==N_NODES gets total (v=0 there)
    if (i < N_NODES) {
        cursor[i] = excl;
        deg[i] = rsqrtf(deg[i]);             // deg >= 1
    }
}

__global__ __launch_bounds__(256) void k_fill(const int* __restrict__ ei,
                                              const float* __restrict__ ew,
                                              const float* __restrict__ dis,
                                              int* __restrict__ cursor,
                                              int* __restrict__ srcs,
                                              float* __restrict__ wts) {
    int e = blockIdx.x * 256 + threadIdx.x;
    if (e >= N_EDGES) return;
    int r = ei[e];
    int c = ei[N_EDGES + e];
    int pos = atomicAdd(&cursor[c], 1);
    srcs[pos] = r;
    wts[pos] = ew[e] * dis[r];
}

// node fp32 -> bf16, rows >= N_NODES zero-padded
__global__ __launch_bounds__(256) void k_cast(const float* __restrict__ node,
                                              short* __restrict__ nodeB) {
    size_t idx = (size_t)blockIdx.x * 256 + threadIdx.x;
    size_t base = idx * 8;
    int row = (int)(base >> 9);
    int4 o;
    if (row >= N_NODES) {
        o = make_int4(0, 0, 0, 0);
    } else {
        float4 a = *(const float4*)&node[base];
        float4 c = *(const float4*)&node[base + 4];
        o.x = ((unsigned)f2bf(a.y) << 16) | f2bf(a.x);
        o.y = ((unsigned)f2bf(a.w) << 16) | f2bf(a.z);
        o.z = ((unsigned)f2bf(c.y) << 16) | f2bf(c.x);
        o.w = ((unsigned)f2bf(c.w) << 16) | f2bf(c.z);
    }
    *(int4*)&nodeB[base] = o;
}

// W[k][n] fp32 -> Wt[n][k] bf16
__global__ __launch_bounds__(256) void k_prep_w(const float* __restrict__ W,
                                                short* __restrict__ Wt) {
    int i = blockIdx.x * 256 + threadIdx.x;
    int k = i >> 9, n = i & 511;
    Wt[n * 512 + k] = (short)f2bf(W[i]);
}

// ---------- bf16 MFMA GEMM: C[PADN,512] = nodeB @ Wt^T ----------
__global__ __launch_bounds__(256) void k_gemm_mfma(const short* __restrict__ Abf,
                                                   const short* __restrict__ Bt,
                                                   short* __restrict__ Cbf) {
    __shared__ short As[128 * 64];
    __shared__ short Bs[128 * 64];
    const int tid  = threadIdx.x;
    const int wave = tid >> 6;
    const int lane = tid & 63;
    const int l16  = lane & 15;
    const int quad = lane >> 4;
    const int row0 = blockIdx.y * 128;
    const int col0 = blockIdx.x * 128;
    const int mb = (wave >> 1) * 64;
    const int nb = (wave & 1) * 64;

    floatx4 acc[4][4];
    const floatx4 z = {0.f, 0.f, 0.f, 0.f};
#pragma unroll
    for (int i = 0; i < 4; ++i)
#pragma unroll
        for (int j = 0; j < 4; ++j) acc[i][j] = z;

    const int srow = lane >> 3;
    const int scol = (lane & 7) * 8;

    for (int kk = 0; kk < DIM; kk += 64) {
#pragma unroll
        for (int j = 0; j < 4; ++j) {
            int seg = wave * 4 + j;
            int r = seg * 8 + srow;
            __builtin_amdgcn_global_load_lds(
                (const __attribute__((address_space(1))) void*)(Abf + (size_t)(row0 + r) * DIM + kk + scol),
                (__attribute__((address_space(3))) void*)(As + seg * 512 + lane * 8),
                16, 0, 0);
            __builtin_amdgcn_global_load_lds(
                (const __attribute__((address_space(1))) void*)(Bt + (size_t)(col0 + r) * DIM + kk + scol),
                (__attribute__((address_space(3))) void*)(Bs + seg * 512 + lane * 8),
                16, 0, 0);
        }
        __syncthreads();
#pragma unroll
        for (int kh = 0; kh < 2; ++kh) {
            short8 af[4], bfr[4];
#pragma unroll
            for (int i = 0; i < 4; ++i)
                af[i] = *(const short8*)&As[(mb + i * 16 + l16) * 64 + kh * 32 + quad * 8];
#pragma unroll
            for (int j = 0; j < 4; ++j)
                bfr[j] = *(const short8*)&Bs[(nb + j * 16 + l16) * 64 + kh * 32 + quad * 8];
#pragma unroll
            for (int i = 0; i < 4; ++i)
#pragma unroll
                for (int j = 0; j < 4; ++j)
                    acc[i][j] = __builtin_amdgcn_mfma_f32_16x16x32_bf16(af[i], bfr[j], acc[i][j], 0, 0, 0);
        }
        __syncthreads();
    }
#pragma unroll
    for (int i = 0; i < 4; ++i)
#pragma unroll
        for (int j = 0; j < 4; ++j) {
            int col = col0 + nb + j * 16 + l16;
#pragma unroll
            for (int r = 0; r < 4; ++r) {
                int row = row0 + mb + i * 16 + quad * 4 + r;
                Cbf[(size_t)row * DIM + col] = (short)f2bf(acc[i][j][r]);
            }
        }
}

// fused gather: out[n] = node[n] + b + dis[n]*( dis[n]*xW[n] + sum wts[i]*xW[srcs[i]] )
__global__ __launch_bounds__(256) void k_gather(const int* __restrict__ rowptr,
                                                const int* __restrict__ srcs,
                                                const float* __restrict__ wts,
                                                const short* __restrict__ xWb,
                                                const float* __restrict__ node,
                                                const float* __restrict__ b,
                                                const float* __restrict__ dis,
                                                float* __restrict__ out) {
    int n = blockIdx.x * 2 + (threadIdx.x >> 7);
    int q = (threadIdx.x & 127) * 4;
    if (n >= N_NODES) return;
    float dn = dis[n];
    int lo = rowptr[n], hi = rowptr[n + 1];
    ushort4 xs = *(const ushort4*)&xWb[(size_t)n * DIM + q];
    float4 acc;
    acc.x = dn * bf2f(xs.x); acc.y = dn * bf2f(xs.y);
    acc.z = dn * bf2f(xs.z); acc.w = dn * bf2f(xs.w);
    for (int i = lo; i < hi; ++i) {
        int s = srcs[i];
        float w = wts[i];
        ushort4 v = *(const ushort4*)&xWb[(size_t)s * DIM + q];
        acc.x += w * bf2f(v.x); acc.y += w * bf2f(v.y);
        acc.z += w * bf2f(v.z); acc.w += w * bf2f(v.w);
    }
    float4 nd = *(const float4*)&node[(size_t)n * DIM + q];
    float4 bb = *(const float4*)&b[q];
    float4 r;
    r.x = nd.x + bb.x + dn * acc.x;
    r.y = nd.y + bb.y + dn * acc.y;
    r.z = nd.z + bb.z + dn * acc.z;
    r.w = nd.w + bb.w + dn * acc.w;
    *(float4*)&out[(size_t)n * DIM + q] = r;
}

// per-graph stats: thread t owns dims t, t+256; sorted batch -> segment flush
__global__ __launch_bounds__(256) void k_stats(const float* __restrict__ h,
                                               const int* __restrict__ batch,
                                               float* __restrict__ Sx,
                                               float* __restrict__ Sxx,
                                               float* __restrict__ cntg) {
    const int CH = 32;
    int n0 = blockIdx.x * CH;
    if (n0 >= N_NODES) return;
    int nEnd = n0 + CH; if (nEnd > N_NODES) nEnd = N_NODES;
    int t = threadIdx.x;
    float sx0 = 0.f, sx1 = 0.f, sxx0 = 0.f, sxx1 = 0.f;
    int cur = batch[n0];
    int seg = 0;
    for (int n = n0; n < nEnd; ++n) {
        int g = batch[n];
        if (g != cur) {
            atomicAdd(&Sx[cur * DIM + t], sx0);
            atomicAdd(&Sx[cur * DIM + t + 256], sx1);
            atomicAdd(&Sxx[cur * DIM + t], sxx0);
            atomicAdd(&Sxx[cur * DIM + t + 256], sxx1);
            if (t == 0) atomicAdd(&cntg[cur], (float)seg);
            sx0 = sx1 = sxx0 = sxx1 = 0.f; seg = 0; cur = g;
        }
        float a = h[(size_t)n * DIM + t];
        float c2 = h[(size_t)n * DIM + t + 256];
        sx0 += a;  sxx0 += a * a;
        sx1 += c2; sxx1 += c2 * c2;
        seg++;
    }
    atomicAdd(&Sx[cur * DIM + t], sx0);
    atomicAdd(&Sx[cur * DIM + t + 256], sx1);
    atomicAdd(&Sxx[cur * DIM + t], sxx0);
    atomicAdd(&Sxx[cur * DIM + t + 256], sxx1);
    if (t == 0) atomicAdd(&cntg[cur], (float)seg);
}

__global__ __launch_bounds__(256) void k_fin(const float* __restrict__ Sx,
                                             const float* __restrict__ Sxx,
                                             const float* __restrict__ cntg,
                                             const float* __restrict__ alpha,
                                             float* __restrict__ mA,
                                             float* __restrict__ inv) {
    int i = blockIdx.x * 256 + threadIdx.x;
    if (i >= N_GRAPHS * DIM) return;
    int d = i & (DIM - 1);
    int g = i >> 9;
    float c = fmaxf(cntg[g], 1.0f);
    float m = Sx[i] / c;
    float ma = m * alpha[d];
    float var = Sxx[i] / c - 2.f * m * ma + ma * ma;
    mA[i] = ma;
    inv[i] = rsqrtf(var + EPSV);
}

__global__ __launch_bounds__(256) void k_norm(float* __restrict__ out,
                                              const int* __restrict__ batch,
                                              const float* __restrict__ mA,
                                              const float* __restrict__ inv,
                                              const float* __restrict__ gw,
                                              const float* __restrict__ gb) {
    size_t idx = (size_t)blockIdx.x * 256 + threadIdx.x;
    int n = (int)(idx >> 7);
    int q = ((int)idx & 127) * 4;
    if (n >= N_NODES) return;
    int g = batch[n];
    float4 h = *(const float4*)&out[(size_t)n * DIM + q];
    float4 ma = *(const float4*)&mA[(size_t)g * DIM + q];
    float4 iv = *(const float4*)&inv[(size_t)g * DIM + q];
    float4 w4 = *(const float4*)&gw[q];
    float4 b4 = *(const float4*)&gb[q];
    float4 r;
    r.x = fmaxf(0.f, (h.x - ma.x) * iv.x * w4.x + b4.x);
    r.y = fmaxf(0.f, (h.y - ma.y) * iv.y * w4.y + b4.y);
    r.z = fmaxf(0.f, (h.z - ma.z) * iv.z * w4.z + b4.z);
    r.w = fmaxf(0.f, (h.w - ma.w) * iv.w * w4.w + b4.w);
    *(float4*)&out[(size_t)n * DIM + q] = r;
}

extern "C" void kernel_launch(void* const* d_in, const int* in_sizes, int n_in,
                              void* d_out, int out_size, void* d_ws, size_t ws_size,
                              hipStream_t stream) {
    const float* node  = (const float*)d_in[0];
    const float* eattr = (const float*)d_in[1];
    const float* W     = (const float*)d_in[2];
    const float* b     = (const float*)d_in[3];
    const float* gw    = (const float*)d_in[4];
    const float* gb    = (const float*)d_in[5];
    const float* alpha = (const float*)d_in[6];
    const int*   ei    = (const int*)d_in[7];
    const int*   batch = (const int*)d_in[8];
    float* out = (float*)d_out;

    short* nodeB = (short*)d_ws;                       // PADN*512 bf16
    short* xWb   = nodeB + (size_t)PADN * DIM;         // PADN*512 bf16
    short* Wt    = xWb + (size_t)PADN * DIM;           // 512*512 bf16
    float* dis   = (float*)(Wt + DIM * DIM);           // 50,000
    float* Sx    = dis + N_NODES;
    float* Sxx   = Sx + N_GRAPHS * DIM;
    float* cntg  = Sxx + N_GRAPHS * DIM;
    float* mA    = cntg + 64;
    float* inv   = mA + N_GRAPHS * DIM;
    float* wts   = inv + N_GRAPHS * DIM;               // 160,000
    int* ecnt    = (int*)(wts + N_EDGES);              // 50,000
    int* rowptr  = ecnt + N_NODES;                     // 50,001
    int* cursor  = rowptr + N_NODES + 1;               // 50,000
    int* srcs    = cursor + N_NODES;                   // 160,000
    int* bsum    = srcs + N_EDGES;                     // NBLK
    int* bbase   = bsum + NBLK;                        // NBLK+1

    k_init<<<196, 256, 0, stream>>>(dis, Sx, Sxx, cntg, ecnt);
    k_deg<<<(N_EDGES + 255) / 256, 256, 0, stream>>>(ei, eattr, dis, ecnt);
    k_scanA<<<NBLK, 256, 0, stream>>>(ecnt, bsum);
    k_scanB<<<1, 256, 0, stream>>>(bsum, bbase);
    k_scanC<<<NBLK, 256, 0, stream>>>(ecnt, bbase, rowptr, cursor, dis);
    k_fill<<<(N_EDGES + 255) / 256, 256, 0, stream>>>(ei, eattr, dis, cursor, srcs, wts);
    k_cast<<<(PADN * DIM / 8 + 255) / 256, 256, 0, stream>>>(node, nodeB);
    k_prep_w<<<(DIM * DIM + 255) / 256, 256, 0, stream>>>(W, Wt);
    dim3 ggrid(4, PADN / 128);
    k_gemm_mfma<<<ggrid, 256, 0, stream>>>(nodeB, Wt, xWb);
    k_gather<<<N_NODES / 2, 256, 0, stream>>>(rowptr, srcs, wts, xWb, node, b, dis, out);
    k_stats<<<(N_NODES + 31) / 32, 256, 0, stream>>>(out, batch, Sx, Sxx, cntg);
    k_fin<<<128, 256, 0, stream>>>(Sx, Sxx, cntg, alpha, mA, inv);
    k_norm<<<25000, 256, 0, stream>>>(out, batch, mA, inv, gw, gb);
}

// Round 5
// 416.739 us; speedup vs baseline: 4.5498x; 1.0049x over previous
//
#include <hip/hip_runtime.h>

// GCN layer: conv = D^-1/2 (A+I) D^-1/2 (x W) + b ; h = x + conv ; GraphNorm ; ReLU
// R4: gather was #1 (77us) with FETCH==compulsory set. Cut the compulsory set:
//  - gather reads bf16 nodeB (51MB) not fp32 node (102MB)
//  - h written bf16 IN-PLACE over nodeB (row read only by its own thread first)
//  - GraphNorm stats fused into gather (32 nodes/block, register seg-flush)
//  - k_norm reads h bf16, writes fp32 out. k_stats kernel removed.

#define N_NODES 50000
#define PADN    50048
#define N_EDGES 160000
#define DIM 512
#define N_GRAPHS 64
#define EPSV 1e-5f
#define NBLK 196            // ceil(50000/256)

typedef short short8 __attribute__((ext_vector_type(8)));
typedef float floatx4 __attribute__((ext_vector_type(4)));

__device__ __forceinline__ unsigned short f2bf(float x) {
    unsigned int u = __float_as_uint(x);
    u += 0x7FFFu + ((u >> 16) & 1u);
    return (unsigned short)(u >> 16);
}
__device__ __forceinline__ float bf2f(unsigned short s) {
    return __uint_as_float(((unsigned int)s) << 16);
}

// ---------- setup ----------
__global__ __launch_bounds__(256) void k_init(float* __restrict__ deg,
                                              float* __restrict__ Sx,
                                              float* __restrict__ Sxx,
                                              float* __restrict__ cntg,
                                              int* __restrict__ ecnt) {
    int i = blockIdx.x * 256 + threadIdx.x;
    if (i < N_NODES) { deg[i] = 1.0f; ecnt[i] = 0; }
    if (i < N_GRAPHS * DIM) { Sx[i] = 0.f; Sxx[i] = 0.f; }
    if (i < N_GRAPHS) cntg[i] = 0.f;
}

__global__ __launch_bounds__(256) void k_deg(const int* __restrict__ ei,
                                             const float* __restrict__ ew,
                                             float* __restrict__ deg,
                                             int* __restrict__ ecnt) {
    int e = blockIdx.x * 256 + threadIdx.x;
    if (e < N_EDGES) {
        int c = ei[N_EDGES + e];
        atomicAdd(&deg[c], ew[e]);
        atomicAdd(&ecnt[c], 1);
    }
}

__global__ __launch_bounds__(256) void k_scanA(const int* __restrict__ ecnt,
                                               int* __restrict__ bsum) {
    int i = blockIdx.x * 256 + threadIdx.x;
    int v = (i < N_NODES) ? ecnt[i] : 0;
#pragma unroll
    for (int off = 32; off; off >>= 1) v += __shfl_down(v, off, 64);
    __shared__ int ws[4];
    if ((threadIdx.x & 63) == 0) ws[threadIdx.x >> 6] = v;
    __syncthreads();
    if (threadIdx.x == 0) bsum[blockIdx.x] = ws[0] + ws[1] + ws[2] + ws[3];
}

__global__ __launch_bounds__(256) void k_scanB(const int* __restrict__ bsum,
                                               int* __restrict__ bbase) {
    __shared__ int s[256];
    int t = threadIdx.x;
    int v = (t < NBLK) ? bsum[t] : 0;
    s[t] = v;
    __syncthreads();
#pragma unroll
    for (int off = 1; off < 256; off <<= 1) {
        int u = (t >= off) ? s[t - off] : 0;
        __syncthreads();
        s[t] += u;
        __syncthreads();
    }
    if (t <= NBLK) bbase[t] = (t == 0) ? 0 : s[t - 1];
}

__global__ __launch_bounds__(256) void k_scanC(const int* __restrict__ ecnt,
                                               const int* __restrict__ bbase,
                                               int* __restrict__ rowptr,
                                               int* __restrict__ cursor,
                                               float* __restrict__ deg) {
    __shared__ int s[256];
    int t = threadIdx.x;
    int i = blockIdx.x * 256 + t;
    int v = (i < N_NODES) ? ecnt[i] : 0;
    s[t] = v;
    __syncthreads();
#pragma unroll
    for (int off = 1; off < 256; off <<= 1) {
        int u = (t >= off) ? s[t - off] : 0;
        __syncthreads();
        s[t] += u;
        __syncthreads();
    }
    int excl = s[t] - v + bbase[blockIdx.x];
    if (i <= N_NODES) rowptr[i] = excl;
    if (i < N_NODES) {
        cursor[i] = excl;
        deg[i] = rsqrtf(deg[i]);
    }
}

__global__ __launch_bounds__(256) void k_fill(const int* __restrict__ ei,
                                              const float* __restrict__ ew,
                                              const float* __restrict__ dis,
                                              int* __restrict__ cursor,
                                              int* __restrict__ srcs,
                                              float* __restrict__ wts) {
    int e = blockIdx.x * 256 + threadIdx.x;
    if (e >= N_EDGES) return;
    int r = ei[e];
    int c = ei[N_EDGES + e];
    int pos = atomicAdd(&cursor[c], 1);
    srcs[pos] = r;
    wts[pos] = ew[e] * dis[r];
}

__global__ __launch_bounds__(256) void k_cast(const float* __restrict__ node,
                                              short* __restrict__ nodeB) {
    size_t idx = (size_t)blockIdx.x * 256 + threadIdx.x;
    size_t base = idx * 8;
    int row = (int)(base >> 9);
    int4 o;
    if (row >= N_NODES) {
        o = make_int4(0, 0, 0, 0);
    } else {
        float4 a = *(const float4*)&node[base];
        float4 c = *(const float4*)&node[base + 4];
        o.x = ((unsigned)f2bf(a.y) << 16) | f2bf(a.x);
        o.y = ((unsigned)f2bf(a.w) << 16) | f2bf(a.z);
        o.z = ((unsigned)f2bf(c.y) << 16) | f2bf(c.x);
        o.w = ((unsigned)f2bf(c.w) << 16) | f2bf(c.z);
    }
    *(int4*)&nodeB[base] = o;
}

__global__ __launch_bounds__(256) void k_prep_w(const float* __restrict__ W,
                                                short* __restrict__ Wt) {
    int i = blockIdx.x * 256 + threadIdx.x;
    int k = i >> 9, n = i & 511;
    Wt[n * 512 + k] = (short)f2bf(W[i]);
}

// ---------- bf16 MFMA GEMM: C[PADN,512] = nodeB @ Wt^T ----------
__global__ __launch_bounds__(256) void k_gemm_mfma(const short* __restrict__ Abf,
                                                   const short* __restrict__ Bt,
                                                   short* __restrict__ Cbf) {
    __shared__ short As[128 * 64];
    __shared__ short Bs[128 * 64];
    const int tid  = threadIdx.x;
    const int wave = tid >> 6;
    const int lane = tid & 63;
    const int l16  = lane & 15;
    const int quad = lane >> 4;
    const int row0 = blockIdx.y * 128;
    const int col0 = blockIdx.x * 128;
    const int mb = (wave >> 1) * 64;
    const int nb = (wave & 1) * 64;

    floatx4 acc[4][4];
    const floatx4 z = {0.f, 0.f, 0.f, 0.f};
#pragma unroll
    for (int i = 0; i < 4; ++i)
#pragma unroll
        for (int j = 0; j < 4; ++j) acc[i][j] = z;

    const int srow = lane >> 3;
    const int scol = (lane & 7) * 8;

    for (int kk = 0; kk < DIM; kk += 64) {
#pragma unroll
        for (int j = 0; j < 4; ++j) {
            int seg = wave * 4 + j;
            int r = seg * 8 + srow;
            __builtin_amdgcn_global_load_lds(
                (const __attribute__((address_space(1))) void*)(Abf + (size_t)(row0 + r) * DIM + kk + scol),
                (__attribute__((address_space(3))) void*)(As + seg * 512 + lane * 8),
                16, 0, 0);
            __builtin_amdgcn_global_load_lds(
                (const __attribute__((address_space(1))) void*)(Bt + (size_t)(col0 + r) * DIM + kk + scol),
                (__attribute__((address_space(3))) void*)(Bs + seg * 512 + lane * 8),
                16, 0, 0);
        }
        __syncthreads();
#pragma unroll
        for (int kh = 0; kh < 2; ++kh) {
            short8 af[4], bfr[4];
#pragma unroll
            for (int i = 0; i < 4; ++i)
                af[i] = *(const short8*)&As[(mb + i * 16 + l16) * 64 + kh * 32 + quad * 8];
#pragma unroll
            for (int j = 0; j < 4; ++j)
                bfr[j] = *(const short8*)&Bs[(nb + j * 16 + l16) * 64 + kh * 32 + quad * 8];
#pragma unroll
            for (int i = 0; i < 4; ++i)
#pragma unroll
                for (int j = 0; j < 4; ++j)
                    acc[i][j] = __builtin_amdgcn_mfma_f32_16x16x32_bf16(af[i], bfr[j], acc[i][j], 0, 0, 0);
        }
        __syncthreads();
    }
#pragma unroll
    for (int i = 0; i < 4; ++i)
#pragma unroll
        for (int j = 0; j < 4; ++j) {
            int col = col0 + nb + j * 16 + l16;
#pragma unroll
            for (int r = 0; r < 4; ++r) {
                int row = row0 + mb + i * 16 + quad * 4 + r;
                Cbf[(size_t)row * DIM + col] = (short)f2bf(acc[i][j][r]);
            }
        }
}

// ---------- fused gather + stats ----------
// 32 consecutive nodes/block; half h (128 threads, wave-aligned) handles nodes
// n0+2r+h. h = nodeB[n] + b + dis[n]*(dis[n]*xW[n] + sum wts*xW[src]) computed
// fp32, written bf16 IN-PLACE over nodeB. Per-thread fp32 Sx/Sxx accumulation
// with sorted-batch segment flush (~1.6M atomics total).
__global__ __launch_bounds__(256) void k_gather_stats(
        const int* __restrict__ rowptr,
        const int* __restrict__ srcs,
        const float* __restrict__ wts,
        const short* __restrict__ xWb,
        short* __restrict__ nodeB,           // in: node bf16 ; out: h bf16
        const float* __restrict__ b,
        const float* __restrict__ dis,
        const int* __restrict__ batch,
        float* __restrict__ Sx,
        float* __restrict__ Sxx,
        float* __restrict__ cntg) {
    const int half = threadIdx.x >> 7;
    const int q = (threadIdx.x & 127) * 4;
    const int lead = (threadIdx.x & 127) == 0;
    const int n0 = blockIdx.x * 32;
    float4 bb = *(const float4*)&b[q];
    float sx0 = 0.f, sx1 = 0.f, sx2 = 0.f, sx3 = 0.f;
    float xx0 = 0.f, xx1 = 0.f, xx2 = 0.f, xx3 = 0.f;
    int cur = -1, cnt = 0;
    for (int r = 0; r < 16; ++r) {
        int n = n0 + r * 2 + half;
        if (n >= N_NODES) break;
        int g = batch[n];
        if (g != cur) {                       // wave-uniform (n uniform per half)
            if (cur >= 0) {
                atomicAdd(&Sx[cur * DIM + q + 0], sx0);
                atomicAdd(&Sx[cur * DIM + q + 1], sx1);
                atomicAdd(&Sx[cur * DIM + q + 2], sx2);
                atomicAdd(&Sx[cur * DIM + q + 3], sx3);
                atomicAdd(&Sxx[cur * DIM + q + 0], xx0);
                atomicAdd(&Sxx[cur * DIM + q + 1], xx1);
                atomicAdd(&Sxx[cur * DIM + q + 2], xx2);
                atomicAdd(&Sxx[cur * DIM + q + 3], xx3);
                if (lead) atomicAdd(&cntg[cur], (float)cnt);
                sx0 = sx1 = sx2 = sx3 = 0.f;
                xx0 = xx1 = xx2 = xx3 = 0.f;
                cnt = 0;
            }
            cur = g;
        }
        float dn = dis[n];
        int lo = rowptr[n], hi = rowptr[n + 1];
        ushort4 xs = *(const ushort4*)&xWb[(size_t)n * DIM + q];
        float a0 = dn * bf2f(xs.x), a1 = dn * bf2f(xs.y);
        float a2 = dn * bf2f(xs.z), a3 = dn * bf2f(xs.w);
        for (int i = lo; i < hi; ++i) {
            int s = srcs[i];
            float w = wts[i];
            ushort4 v = *(const ushort4*)&xWb[(size_t)s * DIM + q];
            a0 += w * bf2f(v.x); a1 += w * bf2f(v.y);
            a2 += w * bf2f(v.z); a3 += w * bf2f(v.w);
        }
        ushort4 nv = *(const ushort4*)&nodeB[(size_t)n * DIM + q];
        float h0 = bf2f(nv.x) + bb.x + dn * a0;
        float h1 = bf2f(nv.y) + bb.y + dn * a1;
        float h2 = bf2f(nv.z) + bb.z + dn * a2;
        float h3 = bf2f(nv.w) + bb.w + dn * a3;
        sx0 += h0; xx0 += h0 * h0;
        sx1 += h1; xx1 += h1 * h1;
        sx2 += h2; xx2 += h2 * h2;
        sx3 += h3; xx3 += h3 * h3;
        cnt++;
        ushort4 hv;
        hv.x = f2bf(h0); hv.y = f2bf(h1); hv.z = f2bf(h2); hv.w = f2bf(h3);
        *(ushort4*)&nodeB[(size_t)n * DIM + q] = hv;
    }
    if (cur >= 0) {
        atomicAdd(&Sx[cur * DIM + q + 0], sx0);
        atomicAdd(&Sx[cur * DIM + q + 1], sx1);
        atomicAdd(&Sx[cur * DIM + q + 2], sx2);
        atomicAdd(&Sx[cur * DIM + q + 3], sx3);
        atomicAdd(&Sxx[cur * DIM + q + 0], xx0);
        atomicAdd(&Sxx[cur * DIM + q + 1], xx1);
        atomicAdd(&Sxx[cur * DIM + q + 2], xx2);
        atomicAdd(&Sxx[cur * DIM + q + 3], xx3);
        if (lead) atomicAdd(&cntg[cur], (float)cnt);
    }
}

__global__ __launch_bounds__(256) void k_fin(const float* __restrict__ Sx,
                                             const float* __restrict__ Sxx,
                                             const float* __restrict__ cntg,
                                             const float* __restrict__ alpha,
                                             float* __restrict__ mA,
                                             float* __restrict__ inv) {
    int i = blockIdx.x * 256 + threadIdx.x;
    if (i >= N_GRAPHS * DIM) return;
    int d = i & (DIM - 1);
    int g = i >> 9;
    float c = fmaxf(cntg[g], 1.0f);
    float m = Sx[i] / c;
    float ma = m * alpha[d];
    float var = Sxx[i] / c - 2.f * m * ma + ma * ma;
    mA[i] = ma;
    inv[i] = rsqrtf(var + EPSV);
}

// normalize + ReLU: reads h bf16 (over nodeB), writes fp32 out
__global__ __launch_bounds__(256) void k_norm(const short* __restrict__ hB,
                                              const int* __restrict__ batch,
                                              const float* __restrict__ mA,
                                              const float* __restrict__ inv,
                                              const float* __restrict__ gw,
                                              const float* __restrict__ gb,
                                              float* __restrict__ out) {
    size_t idx = (size_t)blockIdx.x * 256 + threadIdx.x;
    int n = (int)(idx >> 7);
    int q = ((int)idx & 127) * 4;
    if (n >= N_NODES) return;
    int g = batch[n];
    ushort4 hv = *(const ushort4*)&hB[(size_t)n * DIM + q];
    float4 ma = *(const float4*)&mA[(size_t)g * DIM + q];
    float4 iv = *(const float4*)&inv[(size_t)g * DIM + q];
    float4 w4 = *(const float4*)&gw[q];
    float4 b4 = *(const float4*)&gb[q];
    float4 r;
    r.x = fmaxf(0.f, (bf2f(hv.x) - ma.x) * iv.x * w4.x + b4.x);
    r.y = fmaxf(0.f, (bf2f(hv.y) - ma.y) * iv.y * w4.y + b4.y);
    r.z = fmaxf(0.f, (bf2f(hv.z) - ma.z) * iv.z * w4.z + b4.z);
    r.w = fmaxf(0.f, (bf2f(hv.w) - ma.w) * iv.w * w4.w + b4.w);
    *(float4*)&out[(size_t)n * DIM + q] = r;
}

extern "C" void kernel_launch(void* const* d_in, const int* in_sizes, int n_in,
                              void* d_out, int out_size, void* d_ws, size_t ws_size,
                              hipStream_t stream) {
    const float* node  = (const float*)d_in[0];
    const float* eattr = (const float*)d_in[1];
    const float* W     = (const float*)d_in[2];
    const float* b     = (const float*)d_in[3];
    const float* gw    = (const float*)d_in[4];
    const float* gb    = (const float*)d_in[5];
    const float* alpha = (const float*)d_in[6];
    const int*   ei    = (const int*)d_in[7];
    const int*   batch = (const int*)d_in[8];
    float* out = (float*)d_out;

    short* nodeB = (short*)d_ws;                       // PADN*512 bf16 (becomes h)
    short* xWb   = nodeB + (size_t)PADN * DIM;         // PADN*512 bf16
    short* Wt    = xWb + (size_t)PADN * DIM;           // 512*512 bf16
    float* dis   = (float*)(Wt + DIM * DIM);           // 50,000
    float* Sx    = dis + N_NODES;
    float* Sxx   = Sx + N_GRAPHS * DIM;
    float* cntg  = Sxx + N_GRAPHS * DIM;
    float* mA    = cntg + 64;
    float* inv   = mA + N_GRAPHS * DIM;
    float* wts   = inv + N_GRAPHS * DIM;               // 160,000
    int* ecnt    = (int*)(wts + N_EDGES);              // 50,000
    int* rowptr  = ecnt + N_NODES;                     // 50,001
    int* cursor  = rowptr + N_NODES + 1;               // 50,000
    int* srcs    = cursor + N_NODES;                   // 160,000
    int* bsum    = srcs + N_EDGES;                     // NBLK
    int* bbase   = bsum + NBLK;                        // NBLK+1

    k_init<<<196, 256, 0, stream>>>(dis, Sx, Sxx, cntg, ecnt);
    k_deg<<<(N_EDGES + 255) / 256, 256, 0, stream>>>(ei, eattr, dis, ecnt);
    k_scanA<<<NBLK, 256, 0, stream>>>(ecnt, bsum);
    k_scanB<<<1, 256, 0, stream>>>(bsum, bbase);
    k_scanC<<<NBLK, 256, 0, stream>>>(ecnt, bbase, rowptr, cursor, dis);
    k_fill<<<(N_EDGES + 255) / 256, 256, 0, stream>>>(ei, eattr, dis, cursor, srcs, wts);
    k_cast<<<(PADN * DIM / 8 + 255) / 256, 256, 0, stream>>>(node, nodeB);
    k_prep_w<<<(DIM * DIM + 255) / 256, 256, 0, stream>>>(W, Wt);
    dim3 ggrid(4, PADN / 128);
    k_gemm_mfma<<<ggrid, 256, 0, stream>>>(nodeB, Wt, xWb);
    k_gather_stats<<<(N_NODES + 31) / 32, 256, 0, stream>>>(rowptr, srcs, wts, xWb,
                                                            nodeB, b, dis, batch,
                                                            Sx, Sxx, cntg);
    k_fin<<<128, 256, 0, stream>>>(Sx, Sxx, cntg, alpha, mA, inv);
    k_norm<<<25000, 256, 0, stream>>>(nodeB, batch, mA, inv, gw, gb, out);
}

// Round 6
// 413.170 us; speedup vs baseline: 4.5891x; 1.0086x over previous
//
#include <hip/hip_runtime.h>

// GCN layer: conv = D^-1/2 (A+I) D^-1/2 (x W) + b ; h = x + conv ; GraphNorm ; ReLU
// R5: R4's gather+stats fusion serialized 16 nodes/thread (109us, 2.1TB/s,
// VALU 13%) — un-fused. Gather now wave-per-node (12500 blocks), 16B lane
// loads, readfirstlane -> scalar s_load for CSR walk. Stats separate (bf16 h).
// k_init+k_cast+k_prep_w fused into k_setup; k_fin folded into k_norm.

#define N_NODES 50000
#define PADN    50048
#define N_EDGES 160000
#define DIM 512
#define N_GRAPHS 64
#define EPSV 1e-5f
#define NBLK 196            // ceil(50000/256)

typedef short short8 __attribute__((ext_vector_type(8)));
typedef float floatx4 __attribute__((ext_vector_type(4)));

__device__ __forceinline__ unsigned short f2bf(float x) {
    unsigned int u = __float_as_uint(x);
    u += 0x7FFFu + ((u >> 16) & 1u);
    return (unsigned short)(u >> 16);
}
__device__ __forceinline__ float bf2f(unsigned short s) {
    return __uint_as_float(((unsigned int)s) << 16);
}
__device__ __forceinline__ float bflo(int p) {           // low bf16 of packed pair
    return __uint_as_float(((unsigned int)p) << 16);
}
__device__ __forceinline__ float bfhi(int p) {           // high bf16
    return __uint_as_float(((unsigned int)p) & 0xFFFF0000u);
}

// ---------- setup: init (deg/ecnt/stats) + node cast + W transpose-cast ----------
__global__ __launch_bounds__(256) void k_setup(const float* __restrict__ node,
                                               const float* __restrict__ W,
                                               short* __restrict__ nodeB,
                                               short* __restrict__ Wt,
                                               float* __restrict__ deg,
                                               float* __restrict__ Sx,
                                               float* __restrict__ Sxx,
                                               float* __restrict__ cntg,
                                               int* __restrict__ ecnt) {
    int t = threadIdx.x;
    // cast: 12512 blocks cover PADN*512 bf16, 8 elems/thread
    size_t idx = (size_t)blockIdx.x * 256 + t;
    size_t base = idx * 8;
    int row = (int)(base >> 9);
    int4 o;
    if (row >= N_NODES) {
        o = make_int4(0, 0, 0, 0);
    } else {
        float4 a = *(const float4*)&node[base];
        float4 c = *(const float4*)&node[base + 4];
        o.x = ((unsigned)f2bf(a.y) << 16) | f2bf(a.x);
        o.y = ((unsigned)f2bf(a.w) << 16) | f2bf(a.z);
        o.z = ((unsigned)f2bf(c.y) << 16) | f2bf(c.x);
        o.w = ((unsigned)f2bf(c.w) << 16) | f2bf(c.z);
    }
    *(int4*)&nodeB[base] = o;
    // W[k][n] -> Wt[n][k] bf16 : first 1024 blocks
    if (blockIdx.x < 1024) {
        int i = blockIdx.x * 256 + t;
        int k = i >> 9, n = i & 511;
        Wt[n * 512 + k] = (short)f2bf(W[i]);
    }
    // init: first 196 blocks
    if (blockIdx.x < NBLK) {
        int i = blockIdx.x * 256 + t;
        if (i < N_NODES) { deg[i] = 1.0f; ecnt[i] = 0; }
        if (i < N_GRAPHS * DIM) { Sx[i] = 0.f; Sxx[i] = 0.f; }
        if (i < N_GRAPHS) cntg[i] = 0.f;
    }
}

__global__ __launch_bounds__(256) void k_deg(const int* __restrict__ ei,
                                             const float* __restrict__ ew,
                                             float* __restrict__ deg,
                                             int* __restrict__ ecnt) {
    int e = blockIdx.x * 256 + threadIdx.x;
    if (e < N_EDGES) {
        int c = ei[N_EDGES + e];
        atomicAdd(&deg[c], ew[e]);
        atomicAdd(&ecnt[c], 1);
    }
}

__global__ __launch_bounds__(256) void k_scanA(const int* __restrict__ ecnt,
                                               int* __restrict__ bsum) {
    int i = blockIdx.x * 256 + threadIdx.x;
    int v = (i < N_NODES) ? ecnt[i] : 0;
#pragma unroll
    for (int off = 32; off; off >>= 1) v += __shfl_down(v, off, 64);
    __shared__ int ws[4];
    if ((threadIdx.x & 63) == 0) ws[threadIdx.x >> 6] = v;
    __syncthreads();
    if (threadIdx.x == 0) bsum[blockIdx.x] = ws[0] + ws[1] + ws[2] + ws[3];
}

__global__ __launch_bounds__(256) void k_scanB(const int* __restrict__ bsum,
                                               int* __restrict__ bbase) {
    __shared__ int s[256];
    int t = threadIdx.x;
    int v = (t < NBLK) ? bsum[t] : 0;
    s[t] = v;
    __syncthreads();
#pragma unroll
    for (int off = 1; off < 256; off <<= 1) {
        int u = (t >= off) ? s[t - off] : 0;
        __syncthreads();
        s[t] += u;
        __syncthreads();
    }
    if (t <= NBLK) bbase[t] = (t == 0) ? 0 : s[t - 1];
}

__global__ __launch_bounds__(256) void k_scanC(const int* __restrict__ ecnt,
                                               const int* __restrict__ bbase,
                                               int* __restrict__ rowptr,
                                               int* __restrict__ cursor,
                                               float* __restrict__ deg) {
    __shared__ int s[256];
    int t = threadIdx.x;
    int i = blockIdx.x * 256 + t;
    int v = (i < N_NODES) ? ecnt[i] : 0;
    s[t] = v;
    __syncthreads();
#pragma unroll
    for (int off = 1; off < 256; off <<= 1) {
        int u = (t >= off) ? s[t - off] : 0;
        __syncthreads();
        s[t] += u;
        __syncthreads();
    }
    int excl = s[t] - v + bbase[blockIdx.x];
    if (i <= N_NODES) rowptr[i] = excl;
    if (i < N_NODES) {
        cursor[i] = excl;
        deg[i] = rsqrtf(deg[i]);
    }
}

__global__ __launch_bounds__(256) void k_fill(const int* __restrict__ ei,
                                              const float* __restrict__ ew,
                                              const float* __restrict__ dis,
                                              int* __restrict__ cursor,
                                              int* __restrict__ srcs,
                                              float* __restrict__ wts) {
    int e = blockIdx.x * 256 + threadIdx.x;
    if (e >= N_EDGES) return;
    int r = ei[e];
    int c = ei[N_EDGES + e];
    int pos = atomicAdd(&cursor[c], 1);
    srcs[pos] = r;
    wts[pos] = ew[e] * dis[r];
}

// ---------- bf16 MFMA GEMM: C[PADN,512] = nodeB @ Wt^T ----------
__global__ __launch_bounds__(256) void k_gemm_mfma(const short* __restrict__ Abf,
                                                   const short* __restrict__ Bt,
                                                   short* __restrict__ Cbf) {
    __shared__ short As[128 * 64];
    __shared__ short Bs[128 * 64];
    const int tid  = threadIdx.x;
    const int wave = tid >> 6;
    const int lane = tid & 63;
    const int l16  = lane & 15;
    const int quad = lane >> 4;
    const int row0 = blockIdx.y * 128;
    const int col0 = blockIdx.x * 128;
    const int mb = (wave >> 1) * 64;
    const int nb = (wave & 1) * 64;

    floatx4 acc[4][4];
    const floatx4 z = {0.f, 0.f, 0.f, 0.f};
#pragma unroll
    for (int i = 0; i < 4; ++i)
#pragma unroll
        for (int j = 0; j < 4; ++j) acc[i][j] = z;

    const int srow = lane >> 3;
    const int scol = (lane & 7) * 8;

    for (int kk = 0; kk < DIM; kk += 64) {
#pragma unroll
        for (int j = 0; j < 4; ++j) {
            int seg = wave * 4 + j;
            int r = seg * 8 + srow;
            __builtin_amdgcn_global_load_lds(
                (const __attribute__((address_space(1))) void*)(Abf + (size_t)(row0 + r) * DIM + kk + scol),
                (__attribute__((address_space(3))) void*)(As + seg * 512 + lane * 8),
                16, 0, 0);
            __builtin_amdgcn_global_load_lds(
                (const __attribute__((address_space(1))) void*)(Bt + (size_t)(col0 + r) * DIM + kk + scol),
                (__attribute__((address_space(3))) void*)(Bs + seg * 512 + lane * 8),
                16, 0, 0);
        }
        __syncthreads();
#pragma unroll
        for (int kh = 0; kh < 2; ++kh) {
            short8 af[4], bfr[4];
#pragma unroll
            for (int i = 0; i < 4; ++i)
                af[i] = *(const short8*)&As[(mb + i * 16 + l16) * 64 + kh * 32 + quad * 8];
#pragma unroll
            for (int j = 0; j < 4; ++j)
                bfr[j] = *(const short8*)&Bs[(nb + j * 16 + l16) * 64 + kh * 32 + quad * 8];
#pragma unroll
            for (int i = 0; i < 4; ++i)
#pragma unroll
                for (int j = 0; j < 4; ++j)
                    acc[i][j] = __builtin_amdgcn_mfma_f32_16x16x32_bf16(af[i], bfr[j], acc[i][j], 0, 0, 0);
        }
        __syncthreads();
    }
#pragma unroll
    for (int i = 0; i < 4; ++i)
#pragma unroll
        for (int j = 0; j < 4; ++j) {
            int col = col0 + nb + j * 16 + l16;
#pragma unroll
            for (int r = 0; r < 4; ++r) {
                int row = row0 + mb + i * 16 + quad * 4 + r;
                Cbf[(size_t)row * DIM + col] = (short)f2bf(acc[i][j][r]);
            }
        }
}

// ---------- gather: one wave per node ----------
// lane owns dims lane*8..+7 (16B loads). CSR walk via wave-uniform scalar loads.
// h = nodeB[n] + b + dis[n]*(dis[n]*xW[n] + sum wts[i]*xW[srcs[i]]), bf16 in-place.
__global__ __launch_bounds__(256) void k_gather(const int* __restrict__ rowptr,
                                                const int* __restrict__ srcs,
                                                const float* __restrict__ wts,
                                                const short* __restrict__ xWb,
                                                short* __restrict__ nodeB,
                                                const float* __restrict__ b,
                                                const float* __restrict__ dis) {
    const int lane = threadIdx.x & 63;
    const int n = __builtin_amdgcn_readfirstlane(blockIdx.x * 4 + (threadIdx.x >> 6));
    const int q = lane * 8;
    const float dn = dis[n];
    const int lo = rowptr[n], hi = rowptr[n + 1];

    float a0, a1, a2, a3, a4, a5, a6, a7;
    {
        int4 raw = *(const int4*)&xWb[(size_t)n * DIM + q];
        a0 = dn * bflo(raw.x); a1 = dn * bfhi(raw.x);
        a2 = dn * bflo(raw.y); a3 = dn * bfhi(raw.y);
        a4 = dn * bflo(raw.z); a5 = dn * bfhi(raw.z);
        a6 = dn * bflo(raw.w); a7 = dn * bfhi(raw.w);
    }
    for (int i = lo; i < hi; ++i) {
        int s = srcs[i];           // wave-uniform -> s_load
        float w = wts[i];          // wave-uniform -> s_load
        int4 raw = *(const int4*)&xWb[(size_t)s * DIM + q];
        a0 = fmaf(w, bflo(raw.x), a0); a1 = fmaf(w, bfhi(raw.x), a1);
        a2 = fmaf(w, bflo(raw.y), a2); a3 = fmaf(w, bfhi(raw.y), a3);
        a4 = fmaf(w, bflo(raw.z), a4); a5 = fmaf(w, bfhi(raw.z), a5);
        a6 = fmaf(w, bflo(raw.w), a6); a7 = fmaf(w, bfhi(raw.w), a7);
    }
    int4 nd = *(const int4*)&nodeB[(size_t)n * DIM + q];
    float4 b0 = *(const float4*)&b[q];
    float4 b1 = *(const float4*)&b[q + 4];
    float h0 = bflo(nd.x) + b0.x + dn * a0;
    float h1 = bfhi(nd.x) + b0.y + dn * a1;
    float h2 = bflo(nd.y) + b0.z + dn * a2;
    float h3 = bfhi(nd.y) + b0.w + dn * a3;
    float h4 = bflo(nd.z) + b1.x + dn * a4;
    float h5 = bfhi(nd.z) + b1.y + dn * a5;
    float h6 = bflo(nd.w) + b1.z + dn * a6;
    float h7 = bfhi(nd.w) + b1.w + dn * a7;
    int4 o;
    o.x = ((unsigned)f2bf(h1) << 16) | f2bf(h0);
    o.y = ((unsigned)f2bf(h3) << 16) | f2bf(h2);
    o.z = ((unsigned)f2bf(h5) << 16) | f2bf(h4);
    o.w = ((unsigned)f2bf(h7) << 16) | f2bf(h6);
    *(int4*)&nodeB[(size_t)n * DIM + q] = o;
}

// ---------- per-graph stats from bf16 h ----------
// 32 nodes/block; half (128 thr) handles nodes n0+2r+half; thread owns 4 dims.
__global__ __launch_bounds__(256) void k_stats(const short* __restrict__ hB,
                                               const int* __restrict__ batch,
                                               float* __restrict__ Sx,
                                               float* __restrict__ Sxx,
                                               float* __restrict__ cntg) {
    const int half = threadIdx.x >> 7;
    const int q = (threadIdx.x & 127) * 4;
    const int lead = (threadIdx.x & 127) == 0;
    const int n0 = blockIdx.x * 32;
    float sx0 = 0.f, sx1 = 0.f, sx2 = 0.f, sx3 = 0.f;
    float xx0 = 0.f, xx1 = 0.f, xx2 = 0.f, xx3 = 0.f;
    int cur = -1, cnt = 0;
    for (int r = 0; r < 16; ++r) {
        int n = n0 + r * 2 + half;
        if (n >= N_NODES) break;
        int g = batch[n];
        if (g != cur) {
            if (cur >= 0) {
                atomicAdd(&Sx[cur * DIM + q + 0], sx0);
                atomicAdd(&Sx[cur * DIM + q + 1], sx1);
                atomicAdd(&Sx[cur * DIM + q + 2], sx2);
                atomicAdd(&Sx[cur * DIM + q + 3], sx3);
                atomicAdd(&Sxx[cur * DIM + q + 0], xx0);
                atomicAdd(&Sxx[cur * DIM + q + 1], xx1);
                atomicAdd(&Sxx[cur * DIM + q + 2], xx2);
                atomicAdd(&Sxx[cur * DIM + q + 3], xx3);
                if (lead) atomicAdd(&cntg[cur], (float)cnt);
                sx0 = sx1 = sx2 = sx3 = 0.f;
                xx0 = xx1 = xx2 = xx3 = 0.f;
                cnt = 0;
            }
            cur = g;
        }
        ushort4 hv = *(const ushort4*)&hB[(size_t)n * DIM + q];
        float h0 = bf2f(hv.x), h1 = bf2f(hv.y), h2 = bf2f(hv.z), h3 = bf2f(hv.w);
        sx0 += h0; xx0 += h0 * h0;
        sx1 += h1; xx1 += h1 * h1;
        sx2 += h2; xx2 += h2 * h2;
        sx3 += h3; xx3 += h3 * h3;
        cnt++;
    }
    if (cur >= 0) {
        atomicAdd(&Sx[cur * DIM + q + 0], sx0);
        atomicAdd(&Sx[cur * DIM + q + 1], sx1);
        atomicAdd(&Sx[cur * DIM + q + 2], sx2);
        atomicAdd(&Sx[cur * DIM + q + 3], sx3);
        atomicAdd(&Sxx[cur * DIM + q + 0], xx0);
        atomicAdd(&Sxx[cur * DIM + q + 1], xx1);
        atomicAdd(&Sxx[cur * DIM + q + 2], xx2);
        atomicAdd(&Sxx[cur * DIM + q + 3], xx3);
        if (lead) atomicAdd(&cntg[cur], (float)cnt);
    }
}

// ---------- normalize + ReLU (finalize fused): reads bf16 h, writes fp32 out ----------
__global__ __launch_bounds__(256) void k_norm(const short* __restrict__ hB,
                                              const int* __restrict__ batch,
                                              const float* __restrict__ Sx,
                                              const float* __restrict__ Sxx,
                                              const float* __restrict__ cntg,
                                              const float* __restrict__ alpha,
                                              const float* __restrict__ gw,
                                              const float* __restrict__ gb,
                                              float* __restrict__ out) {
    size_t idx = (size_t)blockIdx.x * 256 + threadIdx.x;
    int n = (int)(idx >> 7);
    int q = ((int)idx & 127) * 4;
    if (n >= N_NODES) return;
    int g = batch[n];
    float c = fmaxf(cntg[g], 1.0f);
    float rc = __builtin_amdgcn_rcpf(c);
    float4 sx = *(const float4*)&Sx[(size_t)g * DIM + q];
    float4 xx = *(const float4*)&Sxx[(size_t)g * DIM + q];
    float4 al = *(const float4*)&alpha[q];
    float4 w4 = *(const float4*)&gw[q];
    float4 b4 = *(const float4*)&gb[q];
    ushort4 hv = *(const ushort4*)&hB[(size_t)n * DIM + q];
    float m0 = sx.x * rc, m1 = sx.y * rc, m2 = sx.z * rc, m3 = sx.w * rc;
    float ma0 = m0 * al.x, ma1 = m1 * al.y, ma2 = m2 * al.z, ma3 = m3 * al.w;
    float iv0 = rsqrtf(xx.x * rc - 2.f * m0 * ma0 + ma0 * ma0 + EPSV);
    float iv1 = rsqrtf(xx.y * rc - 2.f * m1 * ma1 + ma1 * ma1 + EPSV);
    float iv2 = rsqrtf(xx.z * rc - 2.f * m2 * ma2 + ma2 * ma2 + EPSV);
    float iv3 = rsqrtf(xx.w * rc - 2.f * m3 * ma3 + ma3 * ma3 + EPSV);
    float4 r;
    r.x = fmaxf(0.f, (bf2f(hv.x) - ma0) * iv0 * w4.x + b4.x);
    r.y = fmaxf(0.f, (bf2f(hv.y) - ma1) * iv1 * w4.y + b4.y);
    r.z = fmaxf(0.f, (bf2f(hv.z) - ma2) * iv2 * w4.z + b4.z);
    r.w = fmaxf(0.f, (bf2f(hv.w) - ma3) * iv3 * w4.w + b4.w);
    *(float4*)&out[(size_t)n * DIM + q] = r;
}

extern "C" void kernel_launch(void* const* d_in, const int* in_sizes, int n_in,
                              void* d_out, int out_size, void* d_ws, size_t ws_size,
                              hipStream_t stream) {
    const float* node  = (const float*)d_in[0];
    const float* eattr = (const float*)d_in[1];
    const float* W     = (const float*)d_in[2];
    const float* b     = (const float*)d_in[3];
    const float* gw    = (const float*)d_in[4];
    const float* gb    = (const float*)d_in[5];
    const float* alpha = (const float*)d_in[6];
    const int*   ei    = (const int*)d_in[7];
    const int*   batch = (const int*)d_in[8];
    float* out = (float*)d_out;

    short* nodeB = (short*)d_ws;                       // PADN*512 bf16 (becomes h)
    short* xWb   = nodeB + (size_t)PADN * DIM;         // PADN*512 bf16
    short* Wt    = xWb + (size_t)PADN * DIM;           // 512*512 bf16
    float* dis   = (float*)(Wt + DIM * DIM);           // 50,000
    float* Sx    = dis + N_NODES;
    float* Sxx   = Sx + N_GRAPHS * DIM;
    float* cntg  = Sxx + N_GRAPHS * DIM;
    float* wts   = cntg + 64;                          // 160,000
    int* ecnt    = (int*)(wts + N_EDGES);              // 50,000
    int* rowptr  = ecnt + N_NODES;                     // 50,001
    int* cursor  = rowptr + N_NODES + 1;               // 50,000
    int* srcs    = cursor + N_NODES;                   // 160,000
    int* bsum    = srcs + N_EDGES;                     // NBLK
    int* bbase   = bsum + NBLK;                        // NBLK+1

    k_setup<<<PADN * DIM / 8 / 256, 256, 0, stream>>>(node, W, nodeB, Wt,
                                                      dis, Sx, Sxx, cntg, ecnt);
    k_deg<<<(N_EDGES + 255) / 256, 256, 0, stream>>>(ei, eattr, dis, ecnt);
    k_scanA<<<NBLK, 256, 0, stream>>>(ecnt, bsum);
    k_scanB<<<1, 256, 0, stream>>>(bsum, bbase);
    k_scanC<<<NBLK, 256, 0, stream>>>(ecnt, bbase, rowptr, cursor, dis);
    k_fill<<<(N_EDGES + 255) / 256, 256, 0, stream>>>(ei, eattr, dis, cursor, srcs, wts);
    dim3 ggrid(4, PADN / 128);
    k_gemm_mfma<<<ggrid, 256, 0, stream>>>(nodeB, Wt, xWb);
    k_gather<<<N_NODES / 4, 256, 0, stream>>>(rowptr, srcs, wts, xWb, nodeB, b, dis);
    k_stats<<<(N_NODES + 31) / 32, 256, 0, stream>>>(nodeB, batch, Sx, Sxx, cntg);
    k_norm<<<25000, 256, 0, stream>>>(nodeB, batch, Sx, Sxx, cntg, alpha, gw, gb, out);
}